// Round 1
// baseline (5800.829 us; speedup 1.0000x reference)
//
#include <hip/hip_runtime.h>

// ---------------- edge-index detection + conversion ----------------

__global__ void k_detect(const unsigned int* ei, int* flag) {
    if (blockIdx.x == 0 && threadIdx.x == 0) {
        int is64 = 1;
        for (int i = 0; i < 64; ++i) {
            if (ei[2 * i + 1] != 0u) { is64 = 0; break; }
        }
        *flag = is64;
    }
}

__global__ void k_convert(const void* ei, int twoE, const int* flag, int* out) {
    int i = blockIdx.x * blockDim.x + threadIdx.x;
    if (i >= twoE) return;
    if (*flag) out[i] = (int)((const long long*)ei)[i];
    else       out[i] = ((const int*)ei)[i];
}

// ---------------- degree / normalization ----------------

__global__ void k_fill1(float* deg, int n) {
    int i = blockIdx.x * blockDim.x + threadIdx.x;
    if (i < n) deg[i] = 1.0f;   // self-loop
}

__global__ void k_count(const int* __restrict__ dst, int E, float* __restrict__ deg) {
    int e = blockIdx.x * blockDim.x + threadIdx.x;
    if (e < E) unsafeAtomicAdd(&deg[dst[e]], 1.0f);
}

__global__ void k_dinv(const float* __restrict__ deg, float* __restrict__ dinv, int n) {
    int i = blockIdx.x * blockDim.x + threadIdx.x;
    if (i < n) dinv[i] = rsqrtf(deg[i]);
}

// ---------------- generic fp32 tiled GEMM ----------------
// A is a concat of 128-wide parts along K (A0|A1|A2), each [n,128] row-major.
// SUM2: A = A0 + A1 elementwise (K must be 128).
// out[n,F] = op(A @ W + bias) (+ post), W is [K,F] row-major.

template<int K, int F, bool RELU, bool BIAS, bool SUM2, bool POSTADD>
__global__ __launch_bounds__(256) void k_gemm(
    const float* __restrict__ A0, const float* __restrict__ A1, const float* __restrict__ A2,
    const float* __restrict__ W, const float* __restrict__ bias,
    const float* __restrict__ post, float* __restrict__ out, int n)
{
    constexpr int CPT = F / 32;             // cols per thread
    __shared__ float Ws[32][F];
    __shared__ float Xs[32][33];
    const int tid = threadIdx.x;
    const int block_row = blockIdx.x * 32;
    const int cg = tid & 31;                // col group
    const int rg = tid >> 5;                // row group (0..7), rows rg*4..rg*4+3
    float acc[4][CPT];
#pragma unroll
    for (int i = 0; i < 4; ++i)
#pragma unroll
        for (int c = 0; c < CPT; ++c) acc[i][c] = 0.f;

    const int lr = tid >> 3;                // X-load row 0..31
    const int lk = (tid & 7) << 2;          // X-load col 0,4,...,28

    for (int kc = 0; kc < K / 32; ++kc) {
        const float* Ap; int kof;
        if constexpr (K == 128) { Ap = A0; kof = kc << 5; }
        else { int p = kc >> 2; Ap = (p == 0) ? A0 : ((p == 1) ? A1 : A2); kof = (kc & 3) << 5; }
        // stage X tile [32][32]
        {
            int row = block_row + lr;
            float4 v = make_float4(0.f, 0.f, 0.f, 0.f);
            if (row < n) {
                v = *(const float4*)(Ap + (size_t)row * 128 + kof + lk);
                if constexpr (SUM2) {
                    float4 u = *(const float4*)(A1 + (size_t)row * 128 + kof + lk);
                    v.x += u.x; v.y += u.y; v.z += u.z; v.w += u.w;
                }
            }
            Xs[lr][lk + 0] = v.x; Xs[lr][lk + 1] = v.y; Xs[lr][lk + 2] = v.z; Xs[lr][lk + 3] = v.w;
        }
        // stage W tile [32][F]
#pragma unroll
        for (int t = 0; t < F / 32; ++t) {
            int idx = tid + t * 256;                 // float4 slot index
            int kk = idx / (F / 4);
            int j4 = (idx % (F / 4)) << 2;
            *(float4*)&Ws[kk][j4] = *(const float4*)(W + (size_t)(kc * 32 + kk) * F + j4);
        }
        __syncthreads();
#pragma unroll
        for (int kk = 0; kk < 32; ++kk) {
            float wv[CPT];
#pragma unroll
            for (int c = 0; c < CPT; ++c) wv[c] = Ws[kk][cg * CPT + c];
#pragma unroll
            for (int i = 0; i < 4; ++i) {
                float xv = Xs[rg * 4 + i][kk];
#pragma unroll
                for (int c = 0; c < CPT; ++c) acc[i][c] = fmaf(xv, wv[c], acc[i][c]);
            }
        }
        __syncthreads();
    }
#pragma unroll
    for (int i = 0; i < 4; ++i) {
        int row = block_row + rg * 4 + i;
        if (row < n) {
#pragma unroll
            for (int c = 0; c < CPT; ++c) {
                int j = cg * CPT + c;
                float v = acc[i][c];
                if constexpr (BIAS) v += bias[j];
                if constexpr (RELU) v = fmaxf(v, 0.f);
                if constexpr (POSTADD) v += post[(size_t)row * F + j];
                out[(size_t)row * F + j] = v;
            }
        }
    }
}

// ---------------- GCN aggregation ----------------

__global__ void k_selfloop(const float* __restrict__ h, const float* __restrict__ dinv,
                           float* __restrict__ out, int n) {
    int idx = blockIdx.x * blockDim.x + threadIdx.x;   // n*32 float4 chunks
    if (idx >= n * 32) return;
    int row = idx >> 5;
    float s = dinv[row]; s *= s;
    float4 v = ((const float4*)h)[idx];
    v.x *= s; v.y *= s; v.z *= s; v.w *= s;
    ((float4*)out)[idx] = v;
}

__global__ void k_edge_agg(const int* __restrict__ src, const int* __restrict__ dst,
                           const float* __restrict__ dinv, const float* __restrict__ h,
                           float* __restrict__ out, int E) {
    int idx = blockIdx.x * blockDim.x + threadIdx.x;   // E*32 (edge, float4-chunk)
    int e = idx >> 5;
    if (e >= E) return;
    int c = idx & 31;
    int s = src[e], d = dst[e];
    float coef = dinv[s] * dinv[d];
    float4 v = ((const float4*)(h + (size_t)s * 128))[c];
    float* o = out + (size_t)d * 128 + (c << 2);
    unsafeAtomicAdd(o + 0, v.x * coef);
    unsafeAtomicAdd(o + 1, v.y * coef);
    unsafeAtomicAdd(o + 2, v.z * coef);
    unsafeAtomicAdd(o + 3, v.w * coef);
}

__global__ void k_bias_relu(float* __restrict__ x, const float* __restrict__ b, int nq) {
    int idx = blockIdx.x * blockDim.x + threadIdx.x;   // n*32 float4 chunks, F=128
    if (idx >= nq) return;
    int j4 = idx & 31;
    float4 bv = ((const float4*)b)[j4];
    float4 v = ((float4*)x)[idx];
    v.x = fmaxf(v.x + bv.x, 0.f);
    v.y = fmaxf(v.y + bv.y, 0.f);
    v.z = fmaxf(v.z + bv.z, 0.f);
    v.w = fmaxf(v.w + bv.w, 0.f);
    ((float4*)x)[idx] = v;
}

// ---------------- final small GEMM [n,64]@[64,10] ----------------

__global__ void k_final(const float* __restrict__ z7, const float* __restrict__ Wo,
                        const float* __restrict__ bo, float* __restrict__ out, int n) {
    int idx = blockIdx.x * blockDim.x + threadIdx.x;
    if (idx >= n * 10) return;
    int row = idx / 10, j = idx % 10;
    const float* zr = z7 + (size_t)row * 64;
    float acc = bo[j];
#pragma unroll
    for (int k = 0; k < 64; ++k) acc = fmaf(zr[k], Wo[k * 10 + j], acc);
    out[idx] = acc;
}

// ---------------- launch ----------------

extern "C" void kernel_launch(void* const* d_in, const int* in_sizes, int n_in,
                              void* d_out, int out_size, void* d_ws, size_t ws_size,
                              hipStream_t stream) {
    const float* x   = (const float*)d_in[0];
    const float* gx  = (const float*)d_in[1];
    const void*  ei  = d_in[2];
    const float* W1  = (const float*)d_in[3];  const float* b1  = (const float*)d_in[4];
    const float* Wdr = (const float*)d_in[5];  const float* bdr = (const float*)d_in[6];
    const float* Wg1 = (const float*)d_in[7];  const float* bg1 = (const float*)d_in[8];
    const float* Wg2 = (const float*)d_in[9];  const float* bg2 = (const float*)d_in[10];
    const float* W2  = (const float*)d_in[11]; const float* b2  = (const float*)d_in[12];
    const float* W3  = (const float*)d_in[13]; const float* b3  = (const float*)d_in[14];
    const float* Wo  = (const float*)d_in[15]; const float* bo  = (const float*)d_in[16];
    float* out = (float*)d_out;
    const int n = in_sizes[0] / 128;
    const int E = in_sizes[2] / 2;
    const int twoE = 2 * E;

    char* ws = (char*)d_ws;
    size_t off = 0;
    auto alloc = [&](size_t bytes) -> void* {
        void* p = ws + off;
        off = (off + bytes + 255) & ~(size_t)255;
        return p;
    };
    int*   flag = (int*)  alloc(256);
    float* deg  = (float*)alloc((size_t)n * 4);
    float* dinv = (float*)alloc((size_t)n * 4);
    int*   es   = (int*)  alloc((size_t)twoE * 4);
    int*   ed   = es + E;
    float* B0 = (float*)alloc((size_t)n * 128 * 4); // z
    float* B1 = (float*)alloc((size_t)n * 128 * 4); // z0 -> z7
    float* B2 = (float*)alloc((size_t)n * 128 * 4); // h -> t
    float* B3 = (float*)alloc((size_t)n * 128 * 4); // z1
    float* B4 = (float*)alloc((size_t)n * 128 * 4); // z2
    (void)ws_size; (void)n_in; (void)out_size;

    k_detect<<<1, 64, 0, stream>>>((const unsigned int*)ei, flag);
    k_convert<<<(twoE + 255) / 256, 256, 0, stream>>>(ei, twoE, flag, es);
    k_fill1<<<(n + 255) / 256, 256, 0, stream>>>(deg, n);
    k_count<<<(E + 255) / 256, 256, 0, stream>>>(ed, E, deg);
    k_dinv<<<(n + 255) / 256, 256, 0, stream>>>(deg, dinv, n);

    const int gb = (n + 31) / 32;
    // z = relu([x|gx] @ W1 + b1)
    k_gemm<256, 128, true,  true,  false, false><<<gb, 256, 0, stream>>>(x, gx, nullptr, W1, b1, nullptr, B0, n);
    // z0 = z @ Wdr + bdr
    k_gemm<128, 128, false, true,  false, false><<<gb, 256, 0, stream>>>(B0, nullptr, nullptr, Wdr, bdr, nullptr, B1, n);
    // h1 = (z + gx) @ Wg1
    k_gemm<128, 128, false, false, true,  false><<<gb, 256, 0, stream>>>(B0, gx, nullptr, Wg1, nullptr, nullptr, B2, n);
    // z1 = relu(agg(h1) + bg1)
    k_selfloop<<<(n * 32 + 255) / 256, 256, 0, stream>>>(B2, dinv, B3, n);
    k_edge_agg<<<(E * 32 + 255) / 256, 256, 0, stream>>>(es, ed, dinv, B2, B3, E);
    k_bias_relu<<<(n * 32 + 255) / 256, 256, 0, stream>>>(B3, bg1, n * 32);
    // h2 = z1 @ Wg2
    k_gemm<128, 128, false, false, false, false><<<gb, 256, 0, stream>>>(B3, nullptr, nullptr, Wg2, nullptr, nullptr, B2, n);
    // z2 = relu(agg(h2) + bg2)
    k_selfloop<<<(n * 32 + 255) / 256, 256, 0, stream>>>(B2, dinv, B4, n);
    k_edge_agg<<<(E * 32 + 255) / 256, 256, 0, stream>>>(es, ed, dinv, B2, B4, E);
    k_bias_relu<<<(n * 32 + 255) / 256, 256, 0, stream>>>(B4, bg2, n * 32);
    // t = relu([z|z1|z2] @ W2 + b2) + z0
    k_gemm<384, 128, true,  true,  false, true ><<<gb, 256, 0, stream>>>(B0, B3, B4, W2, b2, B1, B2, n);
    // z7 = relu(t @ W3 + b3)
    k_gemm<128, 64,  true,  true,  false, false><<<gb, 256, 0, stream>>>(B2, nullptr, nullptr, W3, b3, nullptr, B1, n);
    // out = z7 @ Wo + bo
    k_final<<<(n * 10 + 255) / 256, 256, 0, stream>>>(B1, Wo, bo, out, n);
}

// Round 2
// 795.048 us; speedup vs baseline: 7.2962x; 7.2962x over previous
//
#include <hip/hip_runtime.h>

// ---------------- edge-index detection + conversion ----------------

__global__ void k_detect(const unsigned int* ei, int* flag) {
    if (blockIdx.x == 0 && threadIdx.x == 0) {
        int is64 = 1;
        for (int i = 0; i < 64; ++i) {
            if (ei[2 * i + 1] != 0u) { is64 = 0; break; }
        }
        *flag = is64;
    }
}

__global__ void k_convert(const void* ei, int twoE, const int* flag, int* out) {
    int i = blockIdx.x * blockDim.x + threadIdx.x;
    if (i >= twoE) return;
    if (*flag) out[i] = (int)((const long long*)ei)[i];
    else       out[i] = ((const int*)ei)[i];
}

// ---------------- CSR build ----------------

__global__ void k_hist(const int* __restrict__ dst, int E, int* __restrict__ cnt) {
    int e = blockIdx.x * blockDim.x + threadIdx.x;
    if (e < E) atomicAdd(&cnt[dst[e]], 1);
}

// single-workgroup scan over n counters; also emits dinv and zeroed cursors
__global__ __launch_bounds__(1024) void k_scan(const int* __restrict__ cnt, int n, int E,
                                               int* __restrict__ rowptr, int* __restrict__ cursor,
                                               float* __restrict__ dinv) {
    __shared__ int part[1024];
    const int t = threadIdx.x;
    const int chunk = (n + 1023) >> 10;
    const int beg = t * chunk;
    const int end = min(beg + chunk, n);
    int s = 0;
    for (int i = beg; i < end; ++i) s += cnt[i];
    part[t] = s;
    __syncthreads();
    for (int off = 1; off < 1024; off <<= 1) {
        int v = (t >= off) ? part[t - off] : 0;
        __syncthreads();
        part[t] += v;
        __syncthreads();
    }
    int run = part[t] - s;   // exclusive base
    for (int i = beg; i < end; ++i) {
        int c = cnt[i];
        rowptr[i] = run;
        cursor[i] = 0;
        dinv[i] = rsqrtf((float)(c + 1));   // +1 self-loop
        run += c;
    }
    if (t == 1023) rowptr[n] = E;
}

__global__ void k_fill_csr(const int* __restrict__ src, const int* __restrict__ dst, int E,
                           const int* __restrict__ rowptr, int* __restrict__ cursor,
                           int* __restrict__ csr) {
    int e = blockIdx.x * blockDim.x + threadIdx.x;
    if (e >= E) return;
    int d = dst[e];
    int pos = atomicAdd(&cursor[d], 1);
    csr[rowptr[d] + pos] = src[e];
}

// ---------------- generic fp32 tiled GEMM ----------------
// A is a concat of 128-wide parts along K (A0|A1|A2), each [n,128] row-major.
// SUM2: A = A0 + A1 elementwise (K must be 128).
// out[n,F] = op(A @ W + bias) (+ post), W is [K,F] row-major.

template<int K, int F, bool RELU, bool BIAS, bool SUM2, bool POSTADD>
__global__ __launch_bounds__(256) void k_gemm(
    const float* __restrict__ A0, const float* __restrict__ A1, const float* __restrict__ A2,
    const float* __restrict__ W, const float* __restrict__ bias,
    const float* __restrict__ post, float* __restrict__ out, int n)
{
    constexpr int CPT = F / 32;             // cols per thread
    __shared__ float Ws[32][F];
    __shared__ float Xs[32][33];
    const int tid = threadIdx.x;
    const int block_row = blockIdx.x * 32;
    const int cg = tid & 31;                // col group
    const int rg = tid >> 5;                // row group (0..7), rows rg*4..rg*4+3
    float acc[4][CPT];
#pragma unroll
    for (int i = 0; i < 4; ++i)
#pragma unroll
        for (int c = 0; c < CPT; ++c) acc[i][c] = 0.f;

    const int lr = tid >> 3;                // X-load row 0..31
    const int lk = (tid & 7) << 2;          // X-load col 0,4,...,28

    for (int kc = 0; kc < K / 32; ++kc) {
        const float* Ap; int kof;
        if constexpr (K == 128) { Ap = A0; kof = kc << 5; }
        else { int p = kc >> 2; Ap = (p == 0) ? A0 : ((p == 1) ? A1 : A2); kof = (kc & 3) << 5; }
        // stage X tile [32][32]
        {
            int row = block_row + lr;
            float4 v = make_float4(0.f, 0.f, 0.f, 0.f);
            if (row < n) {
                v = *(const float4*)(Ap + (size_t)row * 128 + kof + lk);
                if constexpr (SUM2) {
                    float4 u = *(const float4*)(A1 + (size_t)row * 128 + kof + lk);
                    v.x += u.x; v.y += u.y; v.z += u.z; v.w += u.w;
                }
            }
            Xs[lr][lk + 0] = v.x; Xs[lr][lk + 1] = v.y; Xs[lr][lk + 2] = v.z; Xs[lr][lk + 3] = v.w;
        }
        // stage W tile [32][F]
#pragma unroll
        for (int t = 0; t < F / 32; ++t) {
            int idx = tid + t * 256;                 // float4 slot index
            int kk = idx / (F / 4);
            int j4 = (idx % (F / 4)) << 2;
            *(float4*)&Ws[kk][j4] = *(const float4*)(W + (size_t)(kc * 32 + kk) * F + j4);
        }
        __syncthreads();
#pragma unroll
        for (int kk = 0; kk < 32; ++kk) {
            float wv[CPT];
#pragma unroll
            for (int c = 0; c < CPT; ++c) wv[c] = Ws[kk][cg * CPT + c];
#pragma unroll
            for (int i = 0; i < 4; ++i) {
                float xv = Xs[rg * 4 + i][kk];
#pragma unroll
                for (int c = 0; c < CPT; ++c) acc[i][c] = fmaf(xv, wv[c], acc[i][c]);
            }
        }
        __syncthreads();
    }
#pragma unroll
    for (int i = 0; i < 4; ++i) {
        int row = block_row + rg * 4 + i;
        if (row < n) {
#pragma unroll
            for (int c = 0; c < CPT; ++c) {
                int j = cg * CPT + c;
                float v = acc[i][c];
                if constexpr (BIAS) v += bias[j];
                if constexpr (RELU) v = fmaxf(v, 0.f);
                if constexpr (POSTADD) v += post[(size_t)row * F + j];
                out[(size_t)row * F + j] = v;
            }
        }
    }
}

// ---------------- GCN aggregation: CSR gather, fused selfloop+bias+relu ----------------
// out[d] = relu( dinv[d]^2 * h[d] + sum_{s in in(d)} dinv[s]*dinv[d]*h[s] + bias )
// one half-wave (32 threads) per node; each thread owns one float4 chunk of 128.

__global__ __launch_bounds__(256) void k_agg(
    const int* __restrict__ rowptr, const int* __restrict__ csr,
    const float* __restrict__ dinv, const float* __restrict__ h,
    const float* __restrict__ bias, float* __restrict__ out, int n)
{
    const int node = blockIdx.x * 8 + (threadIdx.x >> 5);
    if (node >= n) return;
    const int c = threadIdx.x & 31;
    const float4* hb = (const float4*)h;
    const float dd = dinv[node];
    const int beg = rowptr[node];
    const int end = rowptr[node + 1];

    float4 acc = hb[(size_t)node * 32 + c];
    const float sc = dd * dd;
    acc.x *= sc; acc.y *= sc; acc.z *= sc; acc.w *= sc;

    int j = beg;
    for (; j + 3 < end; j += 4) {
        int s0 = csr[j], s1 = csr[j + 1], s2 = csr[j + 2], s3 = csr[j + 3];
        float c0 = dinv[s0] * dd, c1 = dinv[s1] * dd, c2 = dinv[s2] * dd, c3 = dinv[s3] * dd;
        float4 v0 = hb[(size_t)s0 * 32 + c];
        float4 v1 = hb[(size_t)s1 * 32 + c];
        float4 v2 = hb[(size_t)s2 * 32 + c];
        float4 v3 = hb[(size_t)s3 * 32 + c];
        acc.x = fmaf(v0.x, c0, acc.x); acc.y = fmaf(v0.y, c0, acc.y);
        acc.z = fmaf(v0.z, c0, acc.z); acc.w = fmaf(v0.w, c0, acc.w);
        acc.x = fmaf(v1.x, c1, acc.x); acc.y = fmaf(v1.y, c1, acc.y);
        acc.z = fmaf(v1.z, c1, acc.z); acc.w = fmaf(v1.w, c1, acc.w);
        acc.x = fmaf(v2.x, c2, acc.x); acc.y = fmaf(v2.y, c2, acc.y);
        acc.z = fmaf(v2.z, c2, acc.z); acc.w = fmaf(v2.w, c2, acc.w);
        acc.x = fmaf(v3.x, c3, acc.x); acc.y = fmaf(v3.y, c3, acc.y);
        acc.z = fmaf(v3.z, c3, acc.z); acc.w = fmaf(v3.w, c3, acc.w);
    }
    for (; j < end; ++j) {
        int s = csr[j];
        float co = dinv[s] * dd;
        float4 v = hb[(size_t)s * 32 + c];
        acc.x = fmaf(v.x, co, acc.x); acc.y = fmaf(v.y, co, acc.y);
        acc.z = fmaf(v.z, co, acc.z); acc.w = fmaf(v.w, co, acc.w);
    }

    float4 bv = ((const float4*)bias)[c];
    acc.x = fmaxf(acc.x + bv.x, 0.f);
    acc.y = fmaxf(acc.y + bv.y, 0.f);
    acc.z = fmaxf(acc.z + bv.z, 0.f);
    acc.w = fmaxf(acc.w + bv.w, 0.f);
    ((float4*)out)[(size_t)node * 32 + c] = acc;
}

// ---------------- final small GEMM [n,64]@[64,10] ----------------

__global__ void k_final(const float* __restrict__ z7, const float* __restrict__ Wo,
                        const float* __restrict__ bo, float* __restrict__ out, int n) {
    int idx = blockIdx.x * blockDim.x + threadIdx.x;
    if (idx >= n * 10) return;
    int row = idx / 10, j = idx % 10;
    const float* zr = z7 + (size_t)row * 64;
    float acc = bo[j];
#pragma unroll
    for (int k = 0; k < 64; ++k) acc = fmaf(zr[k], Wo[k * 10 + j], acc);
    out[idx] = acc;
}

// ---------------- launch ----------------

extern "C" void kernel_launch(void* const* d_in, const int* in_sizes, int n_in,
                              void* d_out, int out_size, void* d_ws, size_t ws_size,
                              hipStream_t stream) {
    const float* x   = (const float*)d_in[0];
    const float* gx  = (const float*)d_in[1];
    const void*  ei  = d_in[2];
    const float* W1  = (const float*)d_in[3];  const float* b1  = (const float*)d_in[4];
    const float* Wdr = (const float*)d_in[5];  const float* bdr = (const float*)d_in[6];
    const float* Wg1 = (const float*)d_in[7];  const float* bg1 = (const float*)d_in[8];
    const float* Wg2 = (const float*)d_in[9];  const float* bg2 = (const float*)d_in[10];
    const float* W2  = (const float*)d_in[11]; const float* b2  = (const float*)d_in[12];
    const float* W3  = (const float*)d_in[13]; const float* b3  = (const float*)d_in[14];
    const float* Wo  = (const float*)d_in[15]; const float* bo  = (const float*)d_in[16];
    float* out = (float*)d_out;
    const int n = in_sizes[0] / 128;
    const int E = in_sizes[2] / 2;
    const int twoE = 2 * E;

    char* ws = (char*)d_ws;
    size_t off = 0;
    auto alloc = [&](size_t bytes) -> void* {
        void* p = ws + off;
        off = (off + bytes + 255) & ~(size_t)255;
        return p;
    };
    int*   flag   = (int*)  alloc(256);
    int*   cnt    = (int*)  alloc((size_t)n * 4);
    int*   rowptr = (int*)  alloc(((size_t)n + 1) * 4);
    int*   cursor = (int*)  alloc((size_t)n * 4);
    float* dinv   = (float*)alloc((size_t)n * 4);
    int*   es     = (int*)  alloc((size_t)twoE * 4);
    int*   ed     = es + E;
    int*   csr    = (int*)  alloc((size_t)E * 4);
    float* B0 = (float*)alloc((size_t)n * 128 * 4); // z
    float* B1 = (float*)alloc((size_t)n * 128 * 4); // z0 -> z7
    float* B2 = (float*)alloc((size_t)n * 128 * 4); // h -> t
    float* B3 = (float*)alloc((size_t)n * 128 * 4); // z1
    float* B4 = (float*)alloc((size_t)n * 128 * 4); // z2
    (void)ws_size; (void)n_in; (void)out_size;

    // edge prep + CSR build (shared by both GCN layers)
    k_detect<<<1, 64, 0, stream>>>((const unsigned int*)ei, flag);
    k_convert<<<(twoE + 255) / 256, 256, 0, stream>>>(ei, twoE, flag, es);
    hipMemsetAsync(cnt, 0, (size_t)n * 4, stream);
    k_hist<<<(E + 255) / 256, 256, 0, stream>>>(ed, E, cnt);
    k_scan<<<1, 1024, 0, stream>>>(cnt, n, E, rowptr, cursor, dinv);
    k_fill_csr<<<(E + 255) / 256, 256, 0, stream>>>(es, ed, E, rowptr, cursor, csr);

    const int gb = (n + 31) / 32;
    const int ga = (n + 7) / 8;
    // z = relu([x|gx] @ W1 + b1)
    k_gemm<256, 128, true,  true,  false, false><<<gb, 256, 0, stream>>>(x, gx, nullptr, W1, b1, nullptr, B0, n);
    // z0 = z @ Wdr + bdr
    k_gemm<128, 128, false, true,  false, false><<<gb, 256, 0, stream>>>(B0, nullptr, nullptr, Wdr, bdr, nullptr, B1, n);
    // h1 = (z + gx) @ Wg1
    k_gemm<128, 128, false, false, true,  false><<<gb, 256, 0, stream>>>(B0, gx, nullptr, Wg1, nullptr, nullptr, B2, n);
    // z1 = relu(agg(h1) + bg1)
    k_agg<<<ga, 256, 0, stream>>>(rowptr, csr, dinv, B2, bg1, B3, n);
    // h2 = z1 @ Wg2
    k_gemm<128, 128, false, false, false, false><<<gb, 256, 0, stream>>>(B3, nullptr, nullptr, Wg2, nullptr, nullptr, B2, n);
    // z2 = relu(agg(h2) + bg2)
    k_agg<<<ga, 256, 0, stream>>>(rowptr, csr, dinv, B2, bg2, B4, n);
    // t = relu([z|z1|z2] @ W2 + b2) + z0
    k_gemm<384, 128, true,  true,  false, true ><<<gb, 256, 0, stream>>>(B0, B3, B4, W2, b2, B1, B2, n);
    // z7 = relu(t @ W3 + b3)
    k_gemm<128, 64,  true,  true,  false, false><<<gb, 256, 0, stream>>>(B2, nullptr, nullptr, W3, b3, nullptr, B1, n);
    // out = z7 @ Wo + bo
    k_final<<<(n * 10 + 255) / 256, 256, 0, stream>>>(B1, Wo, bo, out, n);
}

// Round 3
// 711.612 us; speedup vs baseline: 8.1517x; 1.1173x over previous
//
#include <hip/hip_runtime.h>

// ---------------- edge-index detection + conversion (+fused dst histogram) ----------------

__global__ void k_detect(const unsigned int* ei, int* flag) {
    if (blockIdx.x == 0 && threadIdx.x == 0) {
        int is64 = 1;
        for (int i = 0; i < 64; ++i) {
            if (ei[2 * i + 1] != 0u) { is64 = 0; break; }
        }
        *flag = is64;
    }
}

// converts edge_index to int32 and histograms destinations (second half) into cnt
__global__ void k_convert_hist(const void* ei, int twoE, int E, const int* flag,
                               int* __restrict__ out, int* __restrict__ cnt) {
    int i = blockIdx.x * blockDim.x + threadIdx.x;
    if (i >= twoE) return;
    int v;
    if (*flag) v = (int)((const long long*)ei)[i];
    else       v = ((const int*)ei)[i];
    out[i] = v;
    if (i >= E) atomicAdd(&cnt[v], 1);   // dst half
}

// ---------------- parallel scan over cnt -> rowptr (+dinv, cursor) ----------------
// level 1: per-block (512 elems) exclusive scan, block sums out
__global__ __launch_bounds__(512) void k_scan1(const int* __restrict__ cnt, int n,
                                               int* __restrict__ rowptr, int* __restrict__ bsum) {
    __shared__ int part[512];
    const int t = threadIdx.x;
    const int i = blockIdx.x * 512 + t;
    int own = (i < n) ? cnt[i] : 0;
    part[t] = own;
    __syncthreads();
#pragma unroll
    for (int off = 1; off < 512; off <<= 1) {
        int v = (t >= off) ? part[t - off] : 0;
        __syncthreads();
        part[t] += v;
        __syncthreads();
    }
    if (i < n) rowptr[i] = part[t] - own;        // exclusive within block
    if (t == 511) bsum[blockIdx.x] = part[511];  // block total
}

// level 2: single block scans block sums (nb <= 256)
__global__ __launch_bounds__(256) void k_scan2(const int* __restrict__ bsum, int nb,
                                               int* __restrict__ bofs) {
    __shared__ int part[256];
    const int t = threadIdx.x;
    int own = (t < nb) ? bsum[t] : 0;
    part[t] = own;
    __syncthreads();
#pragma unroll
    for (int off = 1; off < 256; off <<= 1) {
        int v = (t >= off) ? part[t - off] : 0;
        __syncthreads();
        part[t] += v;
        __syncthreads();
    }
    if (t < nb) bofs[t] = part[t] - own;         // exclusive
}

// level 3: add block offsets; emit dinv and zeroed cursors; rowptr[n]=E
__global__ void k_scan3(const int* __restrict__ cnt, int n, int E,
                        const int* __restrict__ bofs, int* __restrict__ rowptr,
                        int* __restrict__ cursor, float* __restrict__ dinv) {
    int i = blockIdx.x * blockDim.x + threadIdx.x;
    if (i >= n) return;
    rowptr[i] += bofs[i >> 9];
    cursor[i] = 0;
    dinv[i] = rsqrtf((float)(cnt[i] + 1));       // +1 self-loop
    if (i == 0) rowptr[n] = E;
}

__global__ void k_fill_csr(const int* __restrict__ src, const int* __restrict__ dst, int E,
                           const int* __restrict__ rowptr, int* __restrict__ cursor,
                           int* __restrict__ csr) {
    int e = blockIdx.x * blockDim.x + threadIdx.x;
    if (e >= E) return;
    int d = dst[e];
    int pos = atomicAdd(&cursor[d], 1);
    csr[rowptr[d] + pos] = src[e];
}

// ---------------- generic fp32 tiled GEMM ----------------
// A is a concat of 128-wide parts along K (A0|A1|A2), each [n,128] row-major.
// SUM2: A = A0 + A1 elementwise (K must be 128).
// out[n,F] = op(A @ W + bias) (+ post), W is [K,F] row-major.
// thread (rg,cg) owns rows rg*4..rg*4+3, columns {cg + 32*c} -> LDS bank-conflict-free,
// coalesced stride-1 stores.

template<int K, int F, bool RELU, bool BIAS, bool SUM2, bool POSTADD>
__global__ __launch_bounds__(256) void k_gemm(
    const float* __restrict__ A0, const float* __restrict__ A1, const float* __restrict__ A2,
    const float* __restrict__ W, const float* __restrict__ bias,
    const float* __restrict__ post, float* __restrict__ out, int n)
{
    constexpr int CPT = F / 32;             // cols per thread
    __shared__ float Ws[32][F];
    __shared__ float Xs[32][33];
    const int tid = threadIdx.x;
    const int block_row = blockIdx.x * 32;
    const int cg = tid & 31;                // col group: columns cg + 32*c
    const int rg = tid >> 5;                // row group (0..7), rows rg*4..rg*4+3
    float acc[4][CPT];
#pragma unroll
    for (int i = 0; i < 4; ++i)
#pragma unroll
        for (int c = 0; c < CPT; ++c) acc[i][c] = 0.f;

    const int lr = tid >> 3;                // X-load row 0..31
    const int lk = (tid & 7) << 2;          // X-load col 0,4,...,28

    for (int kc = 0; kc < K / 32; ++kc) {
        const float* Ap; int kof;
        if constexpr (K == 128) { Ap = A0; kof = kc << 5; }
        else { int p = kc >> 2; Ap = (p == 0) ? A0 : ((p == 1) ? A1 : A2); kof = (kc & 3) << 5; }
        // stage X tile [32][32]
        {
            int row = block_row + lr;
            float4 v = make_float4(0.f, 0.f, 0.f, 0.f);
            if (row < n) {
                v = *(const float4*)(Ap + (size_t)row * 128 + kof + lk);
                if constexpr (SUM2) {
                    float4 u = *(const float4*)(A1 + (size_t)row * 128 + kof + lk);
                    v.x += u.x; v.y += u.y; v.z += u.z; v.w += u.w;
                }
            }
            Xs[lr][lk + 0] = v.x; Xs[lr][lk + 1] = v.y; Xs[lr][lk + 2] = v.z; Xs[lr][lk + 3] = v.w;
        }
        // stage W tile [32][F]
#pragma unroll
        for (int t = 0; t < F / 32; ++t) {
            int idx = tid + t * 256;                 // float4 slot index
            int kk = idx / (F / 4);
            int j4 = (idx % (F / 4)) << 2;
            *(float4*)&Ws[kk][j4] = *(const float4*)(W + (size_t)(kc * 32 + kk) * F + j4);
        }
        __syncthreads();
#pragma unroll
        for (int kk = 0; kk < 32; ++kk) {
            float wv[CPT];
#pragma unroll
            for (int c = 0; c < CPT; ++c) wv[c] = Ws[kk][cg + 32 * c];   // bank = cg, conflict-free
#pragma unroll
            for (int i = 0; i < 4; ++i) {
                float xv = Xs[rg * 4 + i][kk];
#pragma unroll
                for (int c = 0; c < CPT; ++c) acc[i][c] = fmaf(xv, wv[c], acc[i][c]);
            }
        }
        __syncthreads();
    }
#pragma unroll
    for (int i = 0; i < 4; ++i) {
        int row = block_row + rg * 4 + i;
        if (row < n) {
#pragma unroll
            for (int c = 0; c < CPT; ++c) {
                int j = cg + 32 * c;
                float v = acc[i][c];
                if constexpr (BIAS) v += bias[j];
                if constexpr (RELU) v = fmaxf(v, 0.f);
                if constexpr (POSTADD) v += post[(size_t)row * F + j];
                out[(size_t)row * F + j] = v;   // stride-1 across lanes
            }
        }
    }
}

// ---------------- GCN aggregation: CSR gather, fused selfloop+bias+relu ----------------
// out[d] = relu( dinv[d]^2 * h[d] + sum_{s in in(d)} dinv[s]*dinv[d]*h[s] + bias )
// one half-wave (32 threads) per node; each thread owns one float4 chunk of 128.

__global__ __launch_bounds__(256) void k_agg(
    const int* __restrict__ rowptr, const int* __restrict__ csr,
    const float* __restrict__ dinv, const float* __restrict__ h,
    const float* __restrict__ bias, float* __restrict__ out, int n)
{
    const int node = blockIdx.x * 8 + (threadIdx.x >> 5);
    if (node >= n) return;
    const int c = threadIdx.x & 31;
    const float4* hb = (const float4*)h;
    const float dd = dinv[node];
    const int beg = rowptr[node];
    const int end = rowptr[node + 1];

    float4 acc = hb[(size_t)node * 32 + c];
    const float sc = dd * dd;
    acc.x *= sc; acc.y *= sc; acc.z *= sc; acc.w *= sc;

    int j = beg;
    for (; j + 3 < end; j += 4) {
        int s0 = csr[j], s1 = csr[j + 1], s2 = csr[j + 2], s3 = csr[j + 3];
        float c0 = dinv[s0] * dd, c1 = dinv[s1] * dd, c2 = dinv[s2] * dd, c3 = dinv[s3] * dd;
        float4 v0 = hb[(size_t)s0 * 32 + c];
        float4 v1 = hb[(size_t)s1 * 32 + c];
        float4 v2 = hb[(size_t)s2 * 32 + c];
        float4 v3 = hb[(size_t)s3 * 32 + c];
        acc.x = fmaf(v0.x, c0, acc.x); acc.y = fmaf(v0.y, c0, acc.y);
        acc.z = fmaf(v0.z, c0, acc.z); acc.w = fmaf(v0.w, c0, acc.w);
        acc.x = fmaf(v1.x, c1, acc.x); acc.y = fmaf(v1.y, c1, acc.y);
        acc.z = fmaf(v1.z, c1, acc.z); acc.w = fmaf(v1.w, c1, acc.w);
        acc.x = fmaf(v2.x, c2, acc.x); acc.y = fmaf(v2.y, c2, acc.y);
        acc.z = fmaf(v2.z, c2, acc.z); acc.w = fmaf(v2.w, c2, acc.w);
        acc.x = fmaf(v3.x, c3, acc.x); acc.y = fmaf(v3.y, c3, acc.y);
        acc.z = fmaf(v3.z, c3, acc.z); acc.w = fmaf(v3.w, c3, acc.w);
    }
    for (; j < end; ++j) {
        int s = csr[j];
        float co = dinv[s] * dd;
        float4 v = hb[(size_t)s * 32 + c];
        acc.x = fmaf(v.x, co, acc.x); acc.y = fmaf(v.y, co, acc.y);
        acc.z = fmaf(v.z, co, acc.z); acc.w = fmaf(v.w, co, acc.w);
    }

    float4 bv = ((const float4*)bias)[c];
    acc.x = fmaxf(acc.x + bv.x, 0.f);
    acc.y = fmaxf(acc.y + bv.y, 0.f);
    acc.z = fmaxf(acc.z + bv.z, 0.f);
    acc.w = fmaxf(acc.w + bv.w, 0.f);
    ((float4*)out)[(size_t)node * 32 + c] = acc;
}

// ---------------- final small GEMM [n,64]@[64,10] ----------------

__global__ __launch_bounds__(256) void k_final(const float* __restrict__ z7, const float* __restrict__ Wo,
                        const float* __restrict__ bo, float* __restrict__ out, int n) {
    __shared__ float Wos[64][10];
    __shared__ float bos[10];
    if (threadIdx.x < 64) {
#pragma unroll
        for (int j = 0; j < 10; ++j) Wos[threadIdx.x][j] = Wo[threadIdx.x * 10 + j];
        if (threadIdx.x < 10) bos[threadIdx.x] = bo[threadIdx.x];
    }
    __syncthreads();
    int idx = blockIdx.x * blockDim.x + threadIdx.x;
    if (idx >= n * 10) return;
    int row = idx / 10, j = idx % 10;
    const float* zr = z7 + (size_t)row * 64;
    float acc = bos[j];
#pragma unroll
    for (int k = 0; k < 64; ++k) acc = fmaf(zr[k], Wos[k][j], acc);
    out[idx] = acc;
}

// ---------------- launch ----------------

extern "C" void kernel_launch(void* const* d_in, const int* in_sizes, int n_in,
                              void* d_out, int out_size, void* d_ws, size_t ws_size,
                              hipStream_t stream) {
    const float* x   = (const float*)d_in[0];
    const float* gx  = (const float*)d_in[1];
    const void*  ei  = d_in[2];
    const float* W1  = (const float*)d_in[3];  const float* b1  = (const float*)d_in[4];
    const float* Wdr = (const float*)d_in[5];  const float* bdr = (const float*)d_in[6];
    const float* Wg1 = (const float*)d_in[7];  const float* bg1 = (const float*)d_in[8];
    const float* Wg2 = (const float*)d_in[9];  const float* bg2 = (const float*)d_in[10];
    const float* W2  = (const float*)d_in[11]; const float* b2  = (const float*)d_in[12];
    const float* W3  = (const float*)d_in[13]; const float* b3  = (const float*)d_in[14];
    const float* Wo  = (const float*)d_in[15]; const float* bo  = (const float*)d_in[16];
    float* out = (float*)d_out;
    const int n = in_sizes[0] / 128;
    const int E = in_sizes[2] / 2;
    const int twoE = 2 * E;
    const int nb = (n + 511) / 512;          // scan level-1 blocks (<=256)

    char* ws = (char*)d_ws;
    size_t off = 0;
    auto alloc = [&](size_t bytes) -> void* {
        void* p = ws + off;
        off = (off + bytes + 255) & ~(size_t)255;
        return p;
    };
    int*   flag   = (int*)  alloc(256);
    int*   cnt    = (int*)  alloc((size_t)n * 4);
    int*   rowptr = (int*)  alloc(((size_t)n + 1) * 4);
    int*   cursor = (int*)  alloc((size_t)n * 4);
    float* dinv   = (float*)alloc((size_t)n * 4);
    int*   bsum   = (int*)  alloc(1024);
    int*   bofs   = (int*)  alloc(1024);
    int*   es     = (int*)  alloc((size_t)twoE * 4);
    int*   ed     = es + E;
    int*   csr    = (int*)  alloc((size_t)E * 4);
    float* B0 = (float*)alloc((size_t)n * 128 * 4); // z
    float* B1 = (float*)alloc((size_t)n * 128 * 4); // z0 -> z7
    float* B2 = (float*)alloc((size_t)n * 128 * 4); // h -> t
    float* B3 = (float*)alloc((size_t)n * 128 * 4); // z1
    float* B4 = (float*)alloc((size_t)n * 128 * 4); // z2
    (void)ws_size; (void)n_in; (void)out_size;

    // edge prep + CSR build (shared by both GCN layers)
    k_detect<<<1, 64, 0, stream>>>((const unsigned int*)ei, flag);
    hipMemsetAsync(cnt, 0, (size_t)n * 4, stream);
    k_convert_hist<<<(twoE + 255) / 256, 256, 0, stream>>>(ei, twoE, E, flag, es, cnt);
    k_scan1<<<nb, 512, 0, stream>>>(cnt, n, rowptr, bsum);
    k_scan2<<<1, 256, 0, stream>>>(bsum, nb, bofs);
    k_scan3<<<(n + 255) / 256, 256, 0, stream>>>(cnt, n, E, bofs, rowptr, cursor, dinv);
    k_fill_csr<<<(E + 255) / 256, 256, 0, stream>>>(es, ed, E, rowptr, cursor, csr);

    const int gb = (n + 31) / 32;
    const int ga = (n + 7) / 8;
    // z = relu([x|gx] @ W1 + b1)
    k_gemm<256, 128, true,  true,  false, false><<<gb, 256, 0, stream>>>(x, gx, nullptr, W1, b1, nullptr, B0, n);
    // z0 = z @ Wdr + bdr
    k_gemm<128, 128, false, true,  false, false><<<gb, 256, 0, stream>>>(B0, nullptr, nullptr, Wdr, bdr, nullptr, B1, n);
    // h1 = (z + gx) @ Wg1
    k_gemm<128, 128, false, false, true,  false><<<gb, 256, 0, stream>>>(B0, gx, nullptr, Wg1, nullptr, nullptr, B2, n);
    // z1 = relu(agg(h1) + bg1)
    k_agg<<<ga, 256, 0, stream>>>(rowptr, csr, dinv, B2, bg1, B3, n);
    // h2 = z1 @ Wg2
    k_gemm<128, 128, false, false, false, false><<<gb, 256, 0, stream>>>(B3, nullptr, nullptr, Wg2, nullptr, nullptr, B2, n);
    // z2 = relu(agg(h2) + bg2)
    k_agg<<<ga, 256, 0, stream>>>(rowptr, csr, dinv, B2, bg2, B4, n);
    // t = relu([z|z1|z2] @ W2 + b2) + z0
    k_gemm<384, 128, true,  true,  false, true ><<<gb, 256, 0, stream>>>(B0, B3, B4, W2, b2, B1, B2, n);
    // z7 = relu(t @ W3 + b3)
    k_gemm<128, 64,  true,  true,  false, false><<<gb, 256, 0, stream>>>(B2, nullptr, nullptr, W3, b3, nullptr, B1, n);
    // out = z7 @ Wo + bo
    k_final<<<(n * 10 + 255) / 256, 256, 0, stream>>>(B1, Wo, bo, out, n);
}

// Round 4
// 577.038 us; speedup vs baseline: 10.0528x; 1.2332x over previous
//
#include <hip/hip_runtime.h>

typedef __attribute__((ext_vector_type(4))) float f32x4;
typedef __attribute__((ext_vector_type(8))) short bf16x8;

// ---------------- edge-index detection + conversion (+fused dst histogram) ----------------

__global__ void k_detect(const unsigned int* ei, int* flag) {
    if (blockIdx.x == 0 && threadIdx.x == 0) {
        int is64 = 1;
        for (int i = 0; i < 64; ++i) {
            if (ei[2 * i + 1] != 0u) { is64 = 0; break; }
        }
        *flag = is64;
    }
}

__global__ void k_convert_hist(const void* ei, int twoE, int E, const int* flag,
                               int* __restrict__ out, int* __restrict__ cnt) {
    int i = blockIdx.x * blockDim.x + threadIdx.x;
    if (i >= twoE) return;
    int v;
    if (*flag) v = (int)((const long long*)ei)[i];
    else       v = ((const int*)ei)[i];
    out[i] = v;
    if (i >= E) atomicAdd(&cnt[v], 1);   // dst half
}

// ---------------- parallel scan over cnt -> rowptr (+dinv, cursor) ----------------

__global__ __launch_bounds__(512) void k_scan1(const int* __restrict__ cnt, int n,
                                               int* __restrict__ rowptr, int* __restrict__ bsum) {
    __shared__ int part[512];
    const int t = threadIdx.x;
    const int i = blockIdx.x * 512 + t;
    int own = (i < n) ? cnt[i] : 0;
    part[t] = own;
    __syncthreads();
#pragma unroll
    for (int off = 1; off < 512; off <<= 1) {
        int v = (t >= off) ? part[t - off] : 0;
        __syncthreads();
        part[t] += v;
        __syncthreads();
    }
    if (i < n) rowptr[i] = part[t] - own;
    if (t == 511) bsum[blockIdx.x] = part[511];
}

__global__ __launch_bounds__(256) void k_scan2(const int* __restrict__ bsum, int nb,
                                               int* __restrict__ bofs) {
    __shared__ int part[256];
    const int t = threadIdx.x;
    int own = (t < nb) ? bsum[t] : 0;
    part[t] = own;
    __syncthreads();
#pragma unroll
    for (int off = 1; off < 256; off <<= 1) {
        int v = (t >= off) ? part[t - off] : 0;
        __syncthreads();
        part[t] += v;
        __syncthreads();
    }
    if (t < nb) bofs[t] = part[t] - own;
}

__global__ void k_scan3(const int* __restrict__ cnt, int n, int E,
                        const int* __restrict__ bofs, int* __restrict__ rowptr,
                        int* __restrict__ cursor, float* __restrict__ dinv) {
    int i = blockIdx.x * blockDim.x + threadIdx.x;
    if (i >= n) return;
    rowptr[i] += bofs[i >> 9];
    cursor[i] = 0;
    dinv[i] = rsqrtf((float)(cnt[i] + 1));
    if (i == 0) rowptr[n] = E;
}

__global__ void k_fill_csr(const int* __restrict__ src, const int* __restrict__ dst, int E,
                           const int* __restrict__ rowptr, int* __restrict__ cursor,
                           int* __restrict__ csr) {
    int e = blockIdx.x * blockDim.x + threadIdx.x;
    if (e >= E) return;
    int d = dst[e];
    int pos = atomicAdd(&cursor[d], 1);
    csr[rowptr[d] + pos] = src[e];
}

// ---------------- weight conversion: fp32 [K,F] -> fragment-ordered bf16 hi/lo ----------------
// fragment slot idx = (ks*(F/16) + ct)*64 + lane; element j in 0..7
// k = ks*32 + (lane>>4)*8 + j ; col = ct*16 + (lane&15)

__global__ void k_wconv(const float* __restrict__ W, int K, int F,
                        unsigned short* __restrict__ WH, unsigned short* __restrict__ WL) {
    int idx = blockIdx.x * blockDim.x + threadIdx.x;
    int total = (K / 32) * (F / 16) * 64;
    if (idx >= total) return;
    int lane = idx & 63;
    int t = idx >> 6;
    int CT = F / 16;
    int ks = t / CT, ct = t % CT;
    int col = ct * 16 + (lane & 15);
    int kbase = ks * 32 + (lane >> 4) * 8;
    bf16x8 h, l;
#pragma unroll
    for (int j = 0; j < 8; ++j) {
        float w = W[(size_t)(kbase + j) * F + col];
        unsigned int u = __float_as_uint(w);
        unsigned short hi = (unsigned short)(u >> 16);          // truncate toward zero
        float r = w - __uint_as_float((unsigned int)hi << 16);
        unsigned short lo = (unsigned short)(__float_as_uint(r) >> 16);
        h[j] = (short)hi;
        l[j] = (short)lo;
    }
    *(bf16x8*)(WH + (size_t)idx * 8) = h;
    *(bf16x8*)(WL + (size_t)idx * 8) = l;
}

// ---------------- MFMA GEMM (split-bf16, fp32-accurate) ----------------
// A: concat of [n,128] fp32 parts along K (SUM2: A = A0+A1, K==128).
// out[n,F] = op(A @ W + bias) (+ post). 4 waves/block, 32 rows/wave, no LDS.

template<int K, int F, bool RELU, bool BIAS, bool SUM2, bool POSTADD>
__global__ __launch_bounds__(256) void k_mgemm(
    const float* __restrict__ A0, const float* __restrict__ A1, const float* __restrict__ A2,
    const unsigned short* __restrict__ WH, const unsigned short* __restrict__ WL,
    const float* __restrict__ bias, const float* __restrict__ post,
    float* __restrict__ out, int n)
{
    constexpr int CT = F / 16;
    const int lane = threadIdx.x & 63;
    const int wave = threadIdx.x >> 6;
    const int row0 = blockIdx.x * 128 + wave * 32;
    const int arow = lane & 15;
    const int kgrp = lane >> 4;

    f32x4 acc[2][CT];
#pragma unroll
    for (int rt = 0; rt < 2; ++rt)
#pragma unroll
        for (int ct = 0; ct < CT; ++ct) acc[rt][ct] = (f32x4)(0.f);

#pragma unroll
    for (int ks = 0; ks < K / 32; ++ks) {
        const float* Ap; int kof;
        if constexpr (K == 128) { Ap = A0; kof = ks * 32; }
        else { int p = ks >> 2; Ap = (p == 0) ? A0 : ((p == 1) ? A1 : A2); kof = (ks & 3) * 32; }

        bf16x8 ah[2], al[2];
#pragma unroll
        for (int rt = 0; rt < 2; ++rt) {
            int row = row0 + rt * 16 + arow;
            if (row >= n) row = n - 1;                       // clamp (stores are guarded)
            const float* p = Ap + (size_t)row * 128 + kof + kgrp * 8;
            f32x4 v0 = *(const f32x4*)p;
            f32x4 v1 = *(const f32x4*)(p + 4);
            if constexpr (SUM2) {
                const float* q = A1 + (size_t)row * 128 + kof + kgrp * 8;
                f32x4 u0 = *(const f32x4*)q;
                f32x4 u1 = *(const f32x4*)(q + 4);
                v0 += u0; v1 += u1;
            }
#pragma unroll
            for (int j = 0; j < 8; ++j) {
                float f = (j < 4) ? v0[j] : v1[j - 4];
                unsigned int u = __float_as_uint(f);
                unsigned short hi = (unsigned short)(u >> 16);
                float r = f - __uint_as_float((unsigned int)hi << 16);
                ah[rt][j] = (short)hi;
                al[rt][j] = (short)(__float_as_uint(r) >> 16);
            }
        }

#pragma unroll
        for (int ct = 0; ct < CT; ++ct) {
            size_t fo = (((size_t)ks * CT + ct) * 64 + lane) * 8;
            bf16x8 bh = *(const bf16x8*)(WH + fo);
            bf16x8 bl = *(const bf16x8*)(WL + fo);
#pragma unroll
            for (int rt = 0; rt < 2; ++rt) {
                acc[rt][ct] = __builtin_amdgcn_mfma_f32_16x16x32_bf16(ah[rt], bh, acc[rt][ct], 0, 0, 0);
                acc[rt][ct] = __builtin_amdgcn_mfma_f32_16x16x32_bf16(al[rt], bh, acc[rt][ct], 0, 0, 0);
                acc[rt][ct] = __builtin_amdgcn_mfma_f32_16x16x32_bf16(ah[rt], bl, acc[rt][ct], 0, 0, 0);
            }
        }
    }

    // epilogue: D layout col=lane&15, row=(lane>>4)*4+reg  [m89-verified]
#pragma unroll
    for (int rt = 0; rt < 2; ++rt) {
#pragma unroll
        for (int ct = 0; ct < CT; ++ct) {
            int j = ct * 16 + arow;
            float bv = 0.f;
            if constexpr (BIAS) bv = bias[j];
#pragma unroll
            for (int r = 0; r < 4; ++r) {
                int row = row0 + rt * 16 + kgrp * 4 + r;
                if (row < n) {
                    float v = acc[rt][ct][r];
                    if constexpr (BIAS) v += bv;
                    if constexpr (RELU) v = fmaxf(v, 0.f);
                    if constexpr (POSTADD) v += post[(size_t)row * F + j];
                    out[(size_t)row * F + j] = v;
                }
            }
        }
    }
}

// ---------------- GCN aggregation: CSR gather, fused selfloop+bias+relu ----------------

__global__ __launch_bounds__(256) void k_agg(
    const int* __restrict__ rowptr, const int* __restrict__ csr,
    const float* __restrict__ dinv, const float* __restrict__ h,
    const float* __restrict__ bias, float* __restrict__ out, int n)
{
    const int node = blockIdx.x * 8 + (threadIdx.x >> 5);
    if (node >= n) return;
    const int c = threadIdx.x & 31;
    const float4* hb = (const float4*)h;
    const float dd = dinv[node];
    const int beg = rowptr[node];
    const int end = rowptr[node + 1];

    float4 acc = hb[(size_t)node * 32 + c];
    const float sc = dd * dd;
    acc.x *= sc; acc.y *= sc; acc.z *= sc; acc.w *= sc;

    int j = beg;
    for (; j + 3 < end; j += 4) {
        int s0 = csr[j], s1 = csr[j + 1], s2 = csr[j + 2], s3 = csr[j + 3];
        float c0 = dinv[s0] * dd, c1 = dinv[s1] * dd, c2 = dinv[s2] * dd, c3 = dinv[s3] * dd;
        float4 v0 = hb[(size_t)s0 * 32 + c];
        float4 v1 = hb[(size_t)s1 * 32 + c];
        float4 v2 = hb[(size_t)s2 * 32 + c];
        float4 v3 = hb[(size_t)s3 * 32 + c];
        acc.x = fmaf(v0.x, c0, acc.x); acc.y = fmaf(v0.y, c0, acc.y);
        acc.z = fmaf(v0.z, c0, acc.z); acc.w = fmaf(v0.w, c0, acc.w);
        acc.x = fmaf(v1.x, c1, acc.x); acc.y = fmaf(v1.y, c1, acc.y);
        acc.z = fmaf(v1.z, c1, acc.z); acc.w = fmaf(v1.w, c1, acc.w);
        acc.x = fmaf(v2.x, c2, acc.x); acc.y = fmaf(v2.y, c2, acc.y);
        acc.z = fmaf(v2.z, c2, acc.z); acc.w = fmaf(v2.w, c2, acc.w);
        acc.x = fmaf(v3.x, c3, acc.x); acc.y = fmaf(v3.y, c3, acc.y);
        acc.z = fmaf(v3.z, c3, acc.z); acc.w = fmaf(v3.w, c3, acc.w);
    }
    for (; j < end; ++j) {
        int s = csr[j];
        float co = dinv[s] * dd;
        float4 v = hb[(size_t)s * 32 + c];
        acc.x = fmaf(v.x, co, acc.x); acc.y = fmaf(v.y, co, acc.y);
        acc.z = fmaf(v.z, co, acc.z); acc.w = fmaf(v.w, co, acc.w);
    }

    float4 bv = ((const float4*)bias)[c];
    acc.x = fmaxf(acc.x + bv.x, 0.f);
    acc.y = fmaxf(acc.y + bv.y, 0.f);
    acc.z = fmaxf(acc.z + bv.z, 0.f);
    acc.w = fmaxf(acc.w + bv.w, 0.f);
    ((float4*)out)[(size_t)node * 32 + c] = acc;
}

// ---------------- final small GEMM [n,64]@[64,10] ----------------

__global__ __launch_bounds__(256) void k_final(const float* __restrict__ z7, const float* __restrict__ Wo,
                        const float* __restrict__ bo, float* __restrict__ out, int n) {
    __shared__ float Wos[64][10];
    __shared__ float bos[10];
    if (threadIdx.x < 64) {
#pragma unroll
        for (int j = 0; j < 10; ++j) Wos[threadIdx.x][j] = Wo[threadIdx.x * 10 + j];
        if (threadIdx.x < 10) bos[threadIdx.x] = bo[threadIdx.x];
    }
    __syncthreads();
    int idx = blockIdx.x * blockDim.x + threadIdx.x;
    if (idx >= n * 10) return;
    int row = idx / 10, j = idx % 10;
    const float* zr = z7 + (size_t)row * 64;
    float acc = bos[j];
#pragma unroll
    for (int k = 0; k < 64; ++k) acc = fmaf(zr[k], Wos[k][j], acc);
    out[idx] = acc;
}

// ---------------- launch ----------------

extern "C" void kernel_launch(void* const* d_in, const int* in_sizes, int n_in,
                              void* d_out, int out_size, void* d_ws, size_t ws_size,
                              hipStream_t stream) {
    const float* x   = (const float*)d_in[0];
    const float* gx  = (const float*)d_in[1];
    const void*  ei  = d_in[2];
    const float* W1  = (const float*)d_in[3];  const float* b1  = (const float*)d_in[4];
    const float* Wdr = (const float*)d_in[5];  const float* bdr = (const float*)d_in[6];
    const float* Wg1 = (const float*)d_in[7];  const float* bg1 = (const float*)d_in[8];
    const float* Wg2 = (const float*)d_in[9];  const float* bg2 = (const float*)d_in[10];
    const float* W2  = (const float*)d_in[11]; const float* b2  = (const float*)d_in[12];
    const float* W3  = (const float*)d_in[13]; const float* b3  = (const float*)d_in[14];
    const float* Wo  = (const float*)d_in[15]; const float* bo  = (const float*)d_in[16];
    float* out = (float*)d_out;
    const int n = in_sizes[0] / 128;
    const int E = in_sizes[2] / 2;
    const int twoE = 2 * E;
    const int nb = (n + 511) / 512;

    char* ws = (char*)d_ws;
    size_t off = 0;
    auto alloc = [&](size_t bytes) -> void* {
        void* p = ws + off;
        off = (off + bytes + 255) & ~(size_t)255;
        return p;
    };
    int*   flag   = (int*)  alloc(256);
    int*   cnt    = (int*)  alloc((size_t)n * 4);
    int*   rowptr = (int*)  alloc(((size_t)n + 1) * 4);
    int*   cursor = (int*)  alloc((size_t)n * 4);
    float* dinv   = (float*)alloc((size_t)n * 4);
    int*   bsum   = (int*)  alloc(1024);
    int*   bofs   = (int*)  alloc(1024);
    int*   es     = (int*)  alloc((size_t)twoE * 4);
    int*   ed     = es + E;
    int*   csr    = (int*)  alloc((size_t)E * 4);
    // bf16 hi/lo weight fragments
    unsigned short* W1H  = (unsigned short*)alloc(256 * 128 * 2);
    unsigned short* W1L  = (unsigned short*)alloc(256 * 128 * 2);
    unsigned short* WdrH = (unsigned short*)alloc(128 * 128 * 2);
    unsigned short* WdrL = (unsigned short*)alloc(128 * 128 * 2);
    unsigned short* Wg1H = (unsigned short*)alloc(128 * 128 * 2);
    unsigned short* Wg1L = (unsigned short*)alloc(128 * 128 * 2);
    unsigned short* Wg2H = (unsigned short*)alloc(128 * 128 * 2);
    unsigned short* Wg2L = (unsigned short*)alloc(128 * 128 * 2);
    unsigned short* W2H  = (unsigned short*)alloc(384 * 128 * 2);
    unsigned short* W2L  = (unsigned short*)alloc(384 * 128 * 2);
    unsigned short* W3H  = (unsigned short*)alloc(128 * 64 * 2);
    unsigned short* W3L  = (unsigned short*)alloc(128 * 64 * 2);
    float* B0 = (float*)alloc((size_t)n * 128 * 4); // z
    float* B1 = (float*)alloc((size_t)n * 128 * 4); // z0 -> z7
    float* B2 = (float*)alloc((size_t)n * 128 * 4); // h -> t
    float* B3 = (float*)alloc((size_t)n * 128 * 4); // z1
    float* B4 = (float*)alloc((size_t)n * 128 * 4); // z2
    (void)ws_size; (void)n_in; (void)out_size;

    // edge prep + CSR build
    k_detect<<<1, 64, 0, stream>>>((const unsigned int*)ei, flag);
    hipMemsetAsync(cnt, 0, (size_t)n * 4, stream);
    k_convert_hist<<<(twoE + 255) / 256, 256, 0, stream>>>(ei, twoE, E, flag, es, cnt);
    k_scan1<<<nb, 512, 0, stream>>>(cnt, n, rowptr, bsum);
    k_scan2<<<1, 256, 0, stream>>>(bsum, nb, bofs);
    k_scan3<<<(n + 255) / 256, 256, 0, stream>>>(cnt, n, E, bofs, rowptr, cursor, dinv);
    k_fill_csr<<<(E + 255) / 256, 256, 0, stream>>>(es, ed, E, rowptr, cursor, csr);

    // weight conversions (tiny)
    k_wconv<<<(256 * 128 + 255) / 256, 256, 0, stream>>>(W1,  256, 128, W1H,  W1L);
    k_wconv<<<(128 * 128 + 255) / 256, 256, 0, stream>>>(Wdr, 128, 128, WdrH, WdrL);
    k_wconv<<<(128 * 128 + 255) / 256, 256, 0, stream>>>(Wg1, 128, 128, Wg1H, Wg1L);
    k_wconv<<<(128 * 128 + 255) / 256, 256, 0, stream>>>(Wg2, 128, 128, Wg2H, Wg2L);
    k_wconv<<<(384 * 128 + 255) / 256, 256, 0, stream>>>(W2,  384, 128, W2H,  W2L);
    k_wconv<<<(128 * 64  + 255) / 256, 256, 0, stream>>>(W3,  128, 64,  W3H,  W3L);

    const int gm = (n + 127) / 128;
    const int ga = (n + 7) / 8;
    // z = relu([x|gx] @ W1 + b1)
    k_mgemm<256, 128, true,  true,  false, false><<<gm, 256, 0, stream>>>(x, gx, nullptr, W1H, W1L, b1, nullptr, B0, n);
    // z0 = z @ Wdr + bdr
    k_mgemm<128, 128, false, true,  false, false><<<gm, 256, 0, stream>>>(B0, nullptr, nullptr, WdrH, WdrL, bdr, nullptr, B1, n);
    // h1 = (z + gx) @ Wg1
    k_mgemm<128, 128, false, false, true,  false><<<gm, 256, 0, stream>>>(B0, gx, nullptr, Wg1H, Wg1L, nullptr, nullptr, B2, n);
    // z1 = relu(agg(h1) + bg1)
    k_agg<<<ga, 256, 0, stream>>>(rowptr, csr, dinv, B2, bg1, B3, n);
    // h2 = z1 @ Wg2
    k_mgemm<128, 128, false, false, false, false><<<gm, 256, 0, stream>>>(B3, nullptr, nullptr, Wg2H, Wg2L, nullptr, nullptr, B2, n);
    // z2 = relu(agg(h2) + bg2)
    k_agg<<<ga, 256, 0, stream>>>(rowptr, csr, dinv, B2, bg2, B4, n);
    // t = relu([z|z1|z2] @ W2 + b2) + z0
    k_mgemm<384, 128, true,  true,  false, true ><<<gm, 256, 0, stream>>>(B0, B3, B4, W2H, W2L, b2, B1, B2, n);
    // z7 = relu(t @ W3 + b3)
    k_mgemm<128, 64,  true,  true,  false, false><<<gm, 256, 0, stream>>>(B2, nullptr, nullptr, W3H, W3L, b3, nullptr, B1, n);
    // out = z7 @ Wo + bo
    k_final<<<(n * 10 + 255) / 256, 256, 0, stream>>>(B1, Wo, bo, out, n);
}

// Round 5
// 459.019 us; speedup vs baseline: 12.6374x; 1.2571x over previous
//
#include <hip/hip_runtime.h>

typedef __attribute__((ext_vector_type(4))) float f32x4;
typedef __attribute__((ext_vector_type(8))) short bf16x8;

// ---------------- edge-index detection + conversion (+fused dst histogram) ----------------

__global__ void k_detect(const unsigned int* ei, int* flag) {
    if (blockIdx.x == 0 && threadIdx.x == 0) {
        int is64 = 1;
        for (int i = 0; i < 64; ++i) {
            if (ei[2 * i + 1] != 0u) { is64 = 0; break; }
        }
        *flag = is64;
    }
}

__global__ void k_convert_hist(const void* ei, int twoE, int E, const int* flag,
                               int* __restrict__ out, int* __restrict__ cnt) {
    int i = blockIdx.x * blockDim.x + threadIdx.x;
    if (i >= twoE) return;
    int v;
    if (*flag) v = (int)((const long long*)ei)[i];
    else       v = ((const int*)ei)[i];
    out[i] = v;
    if (i >= E) atomicAdd(&cnt[v], 1);   // dst half
}

// ---------------- parallel scan over cnt -> rowptr (+dinv, cursor) ----------------

__global__ __launch_bounds__(512) void k_scan1(const int* __restrict__ cnt, int n,
                                               int* __restrict__ rowptr, int* __restrict__ bsum) {
    __shared__ int part[512];
    const int t = threadIdx.x;
    const int i = blockIdx.x * 512 + t;
    int own = (i < n) ? cnt[i] : 0;
    part[t] = own;
    __syncthreads();
#pragma unroll
    for (int off = 1; off < 512; off <<= 1) {
        int v = (t >= off) ? part[t - off] : 0;
        __syncthreads();
        part[t] += v;
        __syncthreads();
    }
    if (i < n) rowptr[i] = part[t] - own;
    if (t == 511) bsum[blockIdx.x] = part[511];
}

__global__ __launch_bounds__(256) void k_scan2(const int* __restrict__ bsum, int nb,
                                               int* __restrict__ bofs) {
    __shared__ int part[256];
    const int t = threadIdx.x;
    int own = (t < nb) ? bsum[t] : 0;
    part[t] = own;
    __syncthreads();
#pragma unroll
    for (int off = 1; off < 256; off <<= 1) {
        int v = (t >= off) ? part[t - off] : 0;
        __syncthreads();
        part[t] += v;
        __syncthreads();
    }
    if (t < nb) bofs[t] = part[t] - own;
}

__global__ void k_scan3(const int* __restrict__ cnt, int n, int E,
                        const int* __restrict__ bofs, int* __restrict__ rowptr,
                        int* __restrict__ cursor, float* __restrict__ dinv) {
    int i = blockIdx.x * blockDim.x + threadIdx.x;
    if (i >= n) return;
    rowptr[i] += bofs[i >> 9];
    cursor[i] = 0;
    dinv[i] = rsqrtf((float)(cnt[i] + 1));
    if (i == 0) rowptr[n] = E;
}

__global__ void k_fill_csr(const int* __restrict__ src, const int* __restrict__ dst, int E,
                           const int* __restrict__ rowptr, int* __restrict__ cursor,
                           int* __restrict__ csr) {
    int e = blockIdx.x * blockDim.x + threadIdx.x;
    if (e >= E) return;
    int d = dst[e];
    int pos = atomicAdd(&cursor[d], 1);
    csr[rowptr[d] + pos] = src[e];
}

// ---------------- weight conversion: fp32 [K,F] -> fragment-ordered bf16 hi/lo ----------------
// fragment slot idx = (ks*(F/16) + ct)*64 + lane; element j in 0..7
// k = ks*32 + (lane>>4)*8 + j ; col = ct*16 + (lane&15)

__global__ void k_wconv(const float* __restrict__ W, int K, int F,
                        unsigned short* __restrict__ WH, unsigned short* __restrict__ WL) {
    int idx = blockIdx.x * blockDim.x + threadIdx.x;
    int total = (K / 32) * (F / 16) * 64;
    if (idx >= total) return;
    int lane = idx & 63;
    int t = idx >> 6;
    int CT = F / 16;
    int ks = t / CT, ct = t % CT;
    int col = ct * 16 + (lane & 15);
    int kbase = ks * 32 + (lane >> 4) * 8;
    bf16x8 h, l;
#pragma unroll
    for (int j = 0; j < 8; ++j) {
        float w = W[(size_t)(kbase + j) * F + col];
        unsigned int u = __float_as_uint(w);
        unsigned short hi = (unsigned short)(u >> 16);          // truncate toward zero
        float r = w - __uint_as_float((unsigned int)hi << 16);
        unsigned short lo = (unsigned short)(__float_as_uint(r) >> 16);
        h[j] = (short)hi;
        l[j] = (short)lo;
    }
    *(bf16x8*)(WH + (size_t)idx * 8) = h;
    *(bf16x8*)(WL + (size_t)idx * 8) = l;
}

// ---------------- MFMA GEMM (split-bf16, fp32-accurate) ----------------
// A: concat of [n,128] fp32 parts along K (SUM2: A = A0+A1, K==128).
// OMODE 0: out fp32 = op(A@W + bias) (+post).  OMODE 1: out bf16 = dinv[row]*(A@W) (RNE).
// 4 waves/block, 32 rows/wave, no LDS.

template<int K, int F, int OMODE, bool RELU, bool BIAS, bool SUM2, bool POSTADD>
__global__ __launch_bounds__(256) void k_mgemm(
    const float* __restrict__ A0, const float* __restrict__ A1, const float* __restrict__ A2,
    const unsigned short* __restrict__ WH, const unsigned short* __restrict__ WL,
    const float* __restrict__ bias, const float* __restrict__ post,
    const float* __restrict__ dinv, void* __restrict__ outv, int n)
{
    constexpr int CT = F / 16;
    const int lane = threadIdx.x & 63;
    const int wave = threadIdx.x >> 6;
    const int row0 = blockIdx.x * 128 + wave * 32;
    const int arow = lane & 15;
    const int kgrp = lane >> 4;

    f32x4 acc[2][CT];
#pragma unroll
    for (int rt = 0; rt < 2; ++rt)
#pragma unroll
        for (int ct = 0; ct < CT; ++ct) acc[rt][ct] = (f32x4)(0.f);

#pragma unroll
    for (int ks = 0; ks < K / 32; ++ks) {
        const float* Ap; int kof;
        if constexpr (K == 128) { Ap = A0; kof = ks * 32; }
        else { int p = ks >> 2; Ap = (p == 0) ? A0 : ((p == 1) ? A1 : A2); kof = (ks & 3) * 32; }

        bf16x8 ah[2], al[2];
#pragma unroll
        for (int rt = 0; rt < 2; ++rt) {
            int row = row0 + rt * 16 + arow;
            if (row >= n) row = n - 1;                       // clamp (stores are guarded)
            const float* p = Ap + (size_t)row * 128 + kof + kgrp * 8;
            f32x4 v0 = *(const f32x4*)p;
            f32x4 v1 = *(const f32x4*)(p + 4);
            if constexpr (SUM2) {
                const float* q = A1 + (size_t)row * 128 + kof + kgrp * 8;
                f32x4 u0 = *(const f32x4*)q;
                f32x4 u1 = *(const f32x4*)(q + 4);
                v0 += u0; v1 += u1;
            }
#pragma unroll
            for (int j = 0; j < 8; ++j) {
                float f = (j < 4) ? v0[j] : v1[j - 4];
                unsigned int u = __float_as_uint(f);
                unsigned short hi = (unsigned short)(u >> 16);
                float r = f - __uint_as_float((unsigned int)hi << 16);
                ah[rt][j] = (short)hi;
                al[rt][j] = (short)(__float_as_uint(r) >> 16);
            }
        }

#pragma unroll
        for (int ct = 0; ct < CT; ++ct) {
            size_t fo = (((size_t)ks * CT + ct) * 64 + lane) * 8;
            bf16x8 bh = *(const bf16x8*)(WH + fo);
            bf16x8 bl = *(const bf16x8*)(WL + fo);
#pragma unroll
            for (int rt = 0; rt < 2; ++rt) {
                acc[rt][ct] = __builtin_amdgcn_mfma_f32_16x16x32_bf16(ah[rt], bh, acc[rt][ct], 0, 0, 0);
                acc[rt][ct] = __builtin_amdgcn_mfma_f32_16x16x32_bf16(al[rt], bh, acc[rt][ct], 0, 0, 0);
                acc[rt][ct] = __builtin_amdgcn_mfma_f32_16x16x32_bf16(ah[rt], bl, acc[rt][ct], 0, 0, 0);
            }
        }
    }

    // epilogue: D layout col=lane&15, row=(lane>>4)*4+reg  [m89-verified]
    if constexpr (OMODE == 1) {
        unsigned short* ob = (unsigned short*)outv;
        float dv[2][4];
#pragma unroll
        for (int rt = 0; rt < 2; ++rt)
#pragma unroll
            for (int r = 0; r < 4; ++r) {
                int row = row0 + rt * 16 + kgrp * 4 + r;
                dv[rt][r] = (row < n) ? dinv[row] : 0.f;
            }
#pragma unroll
        for (int rt = 0; rt < 2; ++rt) {
#pragma unroll
            for (int ct = 0; ct < CT; ++ct) {
                int j = ct * 16 + arow;
#pragma unroll
                for (int r = 0; r < 4; ++r) {
                    int row = row0 + rt * 16 + kgrp * 4 + r;
                    if (row < n) {
                        float v = acc[rt][ct][r] * dv[rt][r];
                        unsigned int u = __float_as_uint(v);
                        u += 0x7fffu + ((u >> 16) & 1u);        // RNE
                        ob[(size_t)row * F + j] = (unsigned short)(u >> 16);
                    }
                }
            }
        }
    } else {
        float* ofp = (float*)outv;
#pragma unroll
        for (int rt = 0; rt < 2; ++rt) {
#pragma unroll
            for (int ct = 0; ct < CT; ++ct) {
                int j = ct * 16 + arow;
                float bv = 0.f;
                if constexpr (BIAS) bv = bias[j];
#pragma unroll
                for (int r = 0; r < 4; ++r) {
                    int row = row0 + rt * 16 + kgrp * 4 + r;
                    if (row < n) {
                        float v = acc[rt][ct][r];
                        if constexpr (BIAS) v += bv;
                        if constexpr (RELU) v = fmaxf(v, 0.f);
                        if constexpr (POSTADD) v += post[(size_t)row * F + j];
                        ofp[(size_t)row * F + j] = v;
                    }
                }
            }
        }
    }
}

// ---------------- GCN aggregation over pre-scaled bf16 features ----------------
// hs[s] = dinv[s]*h[s] in bf16.  out[d] = relu( dinv[d]*(hs[d] + sum_s hs[s]) + bias ).
// half-wave per node; lane owns elements c*4..c*4+3 (8B bf16 loads).

__global__ __launch_bounds__(256) void k_agg_bf(
    const int* __restrict__ rowptr, const int* __restrict__ csr,
    const float* __restrict__ dinv, const unsigned short* __restrict__ hs,
    const float* __restrict__ bias, float* __restrict__ out, int n)
{
    const int node = blockIdx.x * 8 + (threadIdx.x >> 5);
    if (node >= n) return;
    const int c = threadIdx.x & 31;
    const float dd = dinv[node];
    const int beg = rowptr[node];
    const int end = rowptr[node + 1];

    ushort4 sv = *(const ushort4*)(hs + (size_t)node * 128 + c * 4);
    float a0 = __uint_as_float((unsigned int)sv.x << 16);
    float a1 = __uint_as_float((unsigned int)sv.y << 16);
    float a2 = __uint_as_float((unsigned int)sv.z << 16);
    float a3 = __uint_as_float((unsigned int)sv.w << 16);

    int j = beg;
    for (; j + 3 < end; j += 4) {
        int s0 = csr[j], s1 = csr[j + 1], s2 = csr[j + 2], s3 = csr[j + 3];
        ushort4 v0 = *(const ushort4*)(hs + (size_t)s0 * 128 + c * 4);
        ushort4 v1 = *(const ushort4*)(hs + (size_t)s1 * 128 + c * 4);
        ushort4 v2 = *(const ushort4*)(hs + (size_t)s2 * 128 + c * 4);
        ushort4 v3 = *(const ushort4*)(hs + (size_t)s3 * 128 + c * 4);
        a0 += __uint_as_float((unsigned int)v0.x << 16);
        a1 += __uint_as_float((unsigned int)v0.y << 16);
        a2 += __uint_as_float((unsigned int)v0.z << 16);
        a3 += __uint_as_float((unsigned int)v0.w << 16);
        a0 += __uint_as_float((unsigned int)v1.x << 16);
        a1 += __uint_as_float((unsigned int)v1.y << 16);
        a2 += __uint_as_float((unsigned int)v1.z << 16);
        a3 += __uint_as_float((unsigned int)v1.w << 16);
        a0 += __uint_as_float((unsigned int)v2.x << 16);
        a1 += __uint_as_float((unsigned int)v2.y << 16);
        a2 += __uint_as_float((unsigned int)v2.z << 16);
        a3 += __uint_as_float((unsigned int)v2.w << 16);
        a0 += __uint_as_float((unsigned int)v3.x << 16);
        a1 += __uint_as_float((unsigned int)v3.y << 16);
        a2 += __uint_as_float((unsigned int)v3.z << 16);
        a3 += __uint_as_float((unsigned int)v3.w << 16);
    }
    for (; j < end; ++j) {
        int s = csr[j];
        ushort4 v = *(const ushort4*)(hs + (size_t)s * 128 + c * 4);
        a0 += __uint_as_float((unsigned int)v.x << 16);
        a1 += __uint_as_float((unsigned int)v.y << 16);
        a2 += __uint_as_float((unsigned int)v.z << 16);
        a3 += __uint_as_float((unsigned int)v.w << 16);
    }

    float4 bv = ((const float4*)bias)[c];
    float4 o;
    o.x = fmaxf(fmaf(dd, a0, bv.x), 0.f);
    o.y = fmaxf(fmaf(dd, a1, bv.y), 0.f);
    o.z = fmaxf(fmaf(dd, a2, bv.z), 0.f);
    o.w = fmaxf(fmaf(dd, a3, bv.w), 0.f);
    ((float4*)out)[(size_t)node * 32 + c] = o;
}

// ---------------- final small GEMM [n,64]@[64,10] ----------------

__global__ __launch_bounds__(256) void k_final(const float* __restrict__ z7, const float* __restrict__ Wo,
                        const float* __restrict__ bo, float* __restrict__ out, int n) {
    __shared__ float Wos[64][10];
    __shared__ float bos[10];
    if (threadIdx.x < 64) {
#pragma unroll
        for (int j = 0; j < 10; ++j) Wos[threadIdx.x][j] = Wo[threadIdx.x * 10 + j];
        if (threadIdx.x < 10) bos[threadIdx.x] = bo[threadIdx.x];
    }
    __syncthreads();
    int idx = blockIdx.x * blockDim.x + threadIdx.x;
    if (idx >= n * 10) return;
    int row = idx / 10, j = idx % 10;
    const float* zr = z7 + (size_t)row * 64;
    float acc = bos[j];
#pragma unroll
    for (int k = 0; k < 64; ++k) acc = fmaf(zr[k], Wos[k][j], acc);
    out[idx] = acc;
}

// ---------------- launch ----------------

extern "C" void kernel_launch(void* const* d_in, const int* in_sizes, int n_in,
                              void* d_out, int out_size, void* d_ws, size_t ws_size,
                              hipStream_t stream) {
    const float* x   = (const float*)d_in[0];
    const float* gx  = (const float*)d_in[1];
    const void*  ei  = d_in[2];
    const float* W1  = (const float*)d_in[3];  const float* b1  = (const float*)d_in[4];
    const float* Wdr = (const float*)d_in[5];  const float* bdr = (const float*)d_in[6];
    const float* Wg1 = (const float*)d_in[7];  const float* bg1 = (const float*)d_in[8];
    const float* Wg2 = (const float*)d_in[9];  const float* bg2 = (const float*)d_in[10];
    const float* W2  = (const float*)d_in[11]; const float* b2  = (const float*)d_in[12];
    const float* W3  = (const float*)d_in[13]; const float* b3  = (const float*)d_in[14];
    const float* Wo  = (const float*)d_in[15]; const float* bo  = (const float*)d_in[16];
    float* out = (float*)d_out;
    const int n = in_sizes[0] / 128;
    const int E = in_sizes[2] / 2;
    const int twoE = 2 * E;
    const int nb = (n + 511) / 512;

    char* ws = (char*)d_ws;
    size_t off = 0;
    auto alloc = [&](size_t bytes) -> void* {
        void* p = ws + off;
        off = (off + bytes + 255) & ~(size_t)255;
        return p;
    };
    int*   flag   = (int*)  alloc(256);
    int*   cnt    = (int*)  alloc((size_t)n * 4);
    int*   rowptr = (int*)  alloc(((size_t)n + 1) * 4);
    int*   cursor = (int*)  alloc((size_t)n * 4);
    float* dinv   = (float*)alloc((size_t)n * 4);
    int*   bsum   = (int*)  alloc(1024);
    int*   bofs   = (int*)  alloc(1024);
    int*   es     = (int*)  alloc((size_t)twoE * 4);
    int*   ed     = es + E;
    int*   csr    = (int*)  alloc((size_t)E * 4);
    unsigned short* W1H  = (unsigned short*)alloc(256 * 128 * 2);
    unsigned short* W1L  = (unsigned short*)alloc(256 * 128 * 2);
    unsigned short* WdrH = (unsigned short*)alloc(128 * 128 * 2);
    unsigned short* WdrL = (unsigned short*)alloc(128 * 128 * 2);
    unsigned short* Wg1H = (unsigned short*)alloc(128 * 128 * 2);
    unsigned short* Wg1L = (unsigned short*)alloc(128 * 128 * 2);
    unsigned short* Wg2H = (unsigned short*)alloc(128 * 128 * 2);
    unsigned short* Wg2L = (unsigned short*)alloc(128 * 128 * 2);
    unsigned short* W2H  = (unsigned short*)alloc(384 * 128 * 2);
    unsigned short* W2L  = (unsigned short*)alloc(384 * 128 * 2);
    unsigned short* W3H  = (unsigned short*)alloc(128 * 64 * 2);
    unsigned short* W3L  = (unsigned short*)alloc(128 * 64 * 2);
    unsigned short* HS1  = (unsigned short*)alloc((size_t)n * 128 * 2); // dinv-scaled bf16 h1
    unsigned short* HS2  = (unsigned short*)alloc((size_t)n * 128 * 2); // dinv-scaled bf16 h2
    float* B0 = (float*)alloc((size_t)n * 128 * 4); // z
    float* B1 = (float*)alloc((size_t)n * 128 * 4); // z0 -> z7
    float* B2 = (float*)alloc((size_t)n * 128 * 4); // t
    float* B3 = (float*)alloc((size_t)n * 128 * 4); // z1
    float* B4 = (float*)alloc((size_t)n * 128 * 4); // z2
    (void)ws_size; (void)n_in; (void)out_size;

    // edge prep + CSR build
    k_detect<<<1, 64, 0, stream>>>((const unsigned int*)ei, flag);
    hipMemsetAsync(cnt, 0, (size_t)n * 4, stream);
    k_convert_hist<<<(twoE + 255) / 256, 256, 0, stream>>>(ei, twoE, E, flag, es, cnt);
    k_scan1<<<nb, 512, 0, stream>>>(cnt, n, rowptr, bsum);
    k_scan2<<<1, 256, 0, stream>>>(bsum, nb, bofs);
    k_scan3<<<(n + 255) / 256, 256, 0, stream>>>(cnt, n, E, bofs, rowptr, cursor, dinv);
    k_fill_csr<<<(E + 255) / 256, 256, 0, stream>>>(es, ed, E, rowptr, cursor, csr);

    // weight conversions (tiny)
    k_wconv<<<(256 * 128 + 255) / 256, 256, 0, stream>>>(W1,  256, 128, W1H,  W1L);
    k_wconv<<<(128 * 128 + 255) / 256, 256, 0, stream>>>(Wdr, 128, 128, WdrH, WdrL);
    k_wconv<<<(128 * 128 + 255) / 256, 256, 0, stream>>>(Wg1, 128, 128, Wg1H, Wg1L);
    k_wconv<<<(128 * 128 + 255) / 256, 256, 0, stream>>>(Wg2, 128, 128, Wg2H, Wg2L);
    k_wconv<<<(384 * 128 + 255) / 256, 256, 0, stream>>>(W2,  384, 128, W2H,  W2L);
    k_wconv<<<(128 * 64  + 255) / 256, 256, 0, stream>>>(W3,  128, 64,  W3H,  W3L);

    const int gm = (n + 127) / 128;
    const int ga = (n + 7) / 8;
    // z = relu([x|gx] @ W1 + b1)
    k_mgemm<256, 128, 0, true,  true,  false, false><<<gm, 256, 0, stream>>>(x, gx, nullptr, W1H, W1L, b1, nullptr, nullptr, B0, n);
    // z0 = z @ Wdr + bdr
    k_mgemm<128, 128, 0, false, true,  false, false><<<gm, 256, 0, stream>>>(B0, nullptr, nullptr, WdrH, WdrL, bdr, nullptr, nullptr, B1, n);
    // hs1 = dinv * ((z + gx) @ Wg1)   [bf16]
    k_mgemm<128, 128, 1, false, false, true,  false><<<gm, 256, 0, stream>>>(B0, gx, nullptr, Wg1H, Wg1L, nullptr, nullptr, dinv, HS1, n);
    // z1 = relu(dinv * (hs1[d] + sum hs1[s]) + bg1)
    k_agg_bf<<<ga, 256, 0, stream>>>(rowptr, csr, dinv, HS1, bg1, B3, n);
    // hs2 = dinv * (z1 @ Wg2)   [bf16]
    k_mgemm<128, 128, 1, false, false, false, false><<<gm, 256, 0, stream>>>(B3, nullptr, nullptr, Wg2H, Wg2L, nullptr, nullptr, dinv, HS2, n);
    // z2 = relu(dinv * (hs2[d] + sum hs2[s]) + bg2)
    k_agg_bf<<<ga, 256, 0, stream>>>(rowptr, csr, dinv, HS2, bg2, B4, n);
    // t = relu([z|z1|z2] @ W2 + b2) + z0
    k_mgemm<384, 128, 0, true,  true,  false, true ><<<gm, 256, 0, stream>>>(B0, B3, B4, W2H, W2L, b2, B1, nullptr, B2, n);
    // z7 = relu(t @ W3 + b3)
    k_mgemm<128, 64,  0, true,  true,  false, false><<<gm, 256, 0, stream>>>(B2, nullptr, nullptr, W3H, W3L, b3, nullptr, nullptr, B1, n);
    // out = z7 @ Wo + bo
    k_final<<<(n * 10 + 255) / 256, 256, 0, stream>>>(B1, Wo, bo, out, n);
}

// Round 6
// 456.253 us; speedup vs baseline: 12.7141x; 1.0061x over previous
//
#include <hip/hip_runtime.h>

typedef __attribute__((ext_vector_type(4))) float f32x4;
typedef __attribute__((ext_vector_type(8))) short bf16x8;

// ---------------- edge-index detection + conversion (+fused dst histogram) ----------------

__global__ void k_detect(const unsigned int* ei, int* flag) {
    if (blockIdx.x == 0 && threadIdx.x == 0) {
        int is64 = 1;
        for (int i = 0; i < 64; ++i) {
            if (ei[2 * i + 1] != 0u) { is64 = 0; break; }
        }
        *flag = is64;
    }
}

__global__ void k_convert_hist(const void* ei, int twoE, int E, const int* flag,
                               int* __restrict__ out, int* __restrict__ cnt) {
    int i = blockIdx.x * blockDim.x + threadIdx.x;
    if (i >= twoE) return;
    int v;
    if (*flag) v = (int)((const long long*)ei)[i];
    else       v = ((const int*)ei)[i];
    out[i] = v;
    if (i >= E) atomicAdd(&cnt[v], 1);   // dst half
}

// ---------------- parallel scan over cnt -> rowptr (+dinv, cursor) ----------------

__global__ __launch_bounds__(512) void k_scan1(const int* __restrict__ cnt, int n,
                                               int* __restrict__ rowptr, int* __restrict__ bsum) {
    __shared__ int part[512];
    const int t = threadIdx.x;
    const int i = blockIdx.x * 512 + t;
    int own = (i < n) ? cnt[i] : 0;
    part[t] = own;
    __syncthreads();
#pragma unroll
    for (int off = 1; off < 512; off <<= 1) {
        int v = (t >= off) ? part[t - off] : 0;
        __syncthreads();
        part[t] += v;
        __syncthreads();
    }
    if (i < n) rowptr[i] = part[t] - own;
    if (t == 511) bsum[blockIdx.x] = part[511];
}

__global__ __launch_bounds__(256) void k_scan2(const int* __restrict__ bsum, int nb,
                                               int* __restrict__ bofs) {
    __shared__ int part[256];
    const int t = threadIdx.x;
    int own = (t < nb) ? bsum[t] : 0;
    part[t] = own;
    __syncthreads();
#pragma unroll
    for (int off = 1; off < 256; off <<= 1) {
        int v = (t >= off) ? part[t - off] : 0;
        __syncthreads();
        part[t] += v;
        __syncthreads();
    }
    if (t < nb) bofs[t] = part[t] - own;
}

__global__ void k_scan3(const int* __restrict__ cnt, int n, int E,
                        const int* __restrict__ bofs, int* __restrict__ rowptr,
                        int* __restrict__ cursor, float* __restrict__ dinv) {
    int i = blockIdx.x * blockDim.x + threadIdx.x;
    if (i >= n) return;
    rowptr[i] += bofs[i >> 9];
    cursor[i] = 0;
    dinv[i] = rsqrtf((float)(cnt[i] + 1));
    if (i == 0) rowptr[n] = E;
}

// ---------------- CSR fill, dst-range partitioned (write-locality) ----------------
// block's range class = blockIdx & 7; each class owns n/8 of the dst space so its
// CSR write window (~E/8*4B) stays L2-resident and lines fill before eviction.

__global__ __launch_bounds__(256) void k_fill_part(
    const int* __restrict__ src, const int* __restrict__ dst, int E, int n,
    const int* __restrict__ rowptr, int* __restrict__ cursor, int* __restrict__ csr)
{
    const int range = blockIdx.x & 7;
    const int chunk = blockIdx.x >> 3;
    const int nchunks = gridDim.x >> 3;
    const int lo = (int)(((long long)n * range) >> 3);
    const int hi = (int)(((long long)n * (range + 1)) >> 3);
    for (int e = chunk * 256 + threadIdx.x; e < E; e += nchunks * 256) {
        int d = dst[e];
        if (d >= lo && d < hi) {
            int pos = atomicAdd(&cursor[d], 1);
            csr[rowptr[d] + pos] = src[e];
        }
    }
}

// ---------------- weight conversion: fp32 [K,F] -> fragment-ordered bf16 hi/lo ----------------
// fragment slot idx = (ks*(F/16) + ct)*64 + lane; element j in 0..7
// k = ks*32 + (lane>>4)*8 + j ; col = ct*16 + (lane&15)

__global__ void k_wconv(const float* __restrict__ W, int K, int F,
                        unsigned short* __restrict__ WH, unsigned short* __restrict__ WL) {
    int idx = blockIdx.x * blockDim.x + threadIdx.x;
    int total = (K / 32) * (F / 16) * 64;
    if (idx >= total) return;
    int lane = idx & 63;
    int t = idx >> 6;
    int CT = F / 16;
    int ks = t / CT, ct = t % CT;
    int col = ct * 16 + (lane & 15);
    int kbase = ks * 32 + (lane >> 4) * 8;
    bf16x8 h, l;
#pragma unroll
    for (int j = 0; j < 8; ++j) {
        float w = W[(size_t)(kbase + j) * F + col];
        unsigned int u = __float_as_uint(w);
        unsigned short hi = (unsigned short)(u >> 16);          // truncate toward zero
        float r = w - __uint_as_float((unsigned int)hi << 16);
        unsigned short lo = (unsigned short)(__float_as_uint(r) >> 16);
        h[j] = (short)hi;
        l[j] = (short)lo;
    }
    *(bf16x8*)(WH + (size_t)idx * 8) = h;
    *(bf16x8*)(WL + (size_t)idx * 8) = l;
}

// ---------------- MFMA GEMM (split-bf16, fp32-accurate) ----------------
// A: concat of [n,128] fp32 parts along K (SUM2: A = A0+A1, K==128).
// OMODE 0: out fp32 = op(A@W + bias) (+post).  OMODE 1: out bf16 = dinv[row]*(A@W) (RNE).
// 4 waves/block, 32 rows/wave, no LDS.

template<int K, int F, int OMODE, bool RELU, bool BIAS, bool SUM2, bool POSTADD>
__global__ __launch_bounds__(256) void k_mgemm(
    const float* __restrict__ A0, const float* __restrict__ A1, const float* __restrict__ A2,
    const unsigned short* __restrict__ WH, const unsigned short* __restrict__ WL,
    const float* __restrict__ bias, const float* __restrict__ post,
    const float* __restrict__ dinv, void* __restrict__ outv, int n)
{
    constexpr int CT = F / 16;
    const int lane = threadIdx.x & 63;
    const int wave = threadIdx.x >> 6;
    const int row0 = blockIdx.x * 128 + wave * 32;
    const int arow = lane & 15;
    const int kgrp = lane >> 4;

    f32x4 acc[2][CT];
#pragma unroll
    for (int rt = 0; rt < 2; ++rt)
#pragma unroll
        for (int ct = 0; ct < CT; ++ct) acc[rt][ct] = (f32x4)(0.f);

#pragma unroll
    for (int ks = 0; ks < K / 32; ++ks) {
        const float* Ap; int kof;
        if constexpr (K == 128) { Ap = A0; kof = ks * 32; }
        else { int p = ks >> 2; Ap = (p == 0) ? A0 : ((p == 1) ? A1 : A2); kof = (ks & 3) * 32; }

        bf16x8 ah[2], al[2];
#pragma unroll
        for (int rt = 0; rt < 2; ++rt) {
            int row = row0 + rt * 16 + arow;
            if (row >= n) row = n - 1;                       // clamp (stores are guarded)
            const float* p = Ap + (size_t)row * 128 + kof + kgrp * 8;
            f32x4 v0 = *(const f32x4*)p;
            f32x4 v1 = *(const f32x4*)(p + 4);
            if constexpr (SUM2) {
                const float* q = A1 + (size_t)row * 128 + kof + kgrp * 8;
                f32x4 u0 = *(const f32x4*)q;
                f32x4 u1 = *(const f32x4*)(q + 4);
                v0 += u0; v1 += u1;
            }
#pragma unroll
            for (int j = 0; j < 8; ++j) {
                float f = (j < 4) ? v0[j] : v1[j - 4];
                unsigned int u = __float_as_uint(f);
                unsigned short hi = (unsigned short)(u >> 16);
                float r = f - __uint_as_float((unsigned int)hi << 16);
                ah[rt][j] = (short)hi;
                al[rt][j] = (short)(__float_as_uint(r) >> 16);
            }
        }

#pragma unroll
        for (int ct = 0; ct < CT; ++ct) {
            size_t fo = (((size_t)ks * CT + ct) * 64 + lane) * 8;
            bf16x8 bh = *(const bf16x8*)(WH + fo);
            bf16x8 bl = *(const bf16x8*)(WL + fo);
#pragma unroll
            for (int rt = 0; rt < 2; ++rt) {
                acc[rt][ct] = __builtin_amdgcn_mfma_f32_16x16x32_bf16(ah[rt], bh, acc[rt][ct], 0, 0, 0);
                acc[rt][ct] = __builtin_amdgcn_mfma_f32_16x16x32_bf16(al[rt], bh, acc[rt][ct], 0, 0, 0);
                acc[rt][ct] = __builtin_amdgcn_mfma_f32_16x16x32_bf16(ah[rt], bl, acc[rt][ct], 0, 0, 0);
            }
        }
    }

    // epilogue: D layout col=lane&15, row=(lane>>4)*4+reg  [m89-verified]
    if constexpr (OMODE == 1) {
        unsigned short* ob = (unsigned short*)outv;
        float dv[2][4];
#pragma unroll
        for (int rt = 0; rt < 2; ++rt)
#pragma unroll
            for (int r = 0; r < 4; ++r) {
                int row = row0 + rt * 16 + kgrp * 4 + r;
                dv[rt][r] = (row < n) ? dinv[row] : 0.f;
            }
#pragma unroll
        for (int rt = 0; rt < 2; ++rt) {
#pragma unroll
            for (int ct = 0; ct < CT; ++ct) {
                int j = ct * 16 + arow;
#pragma unroll
                for (int r = 0; r < 4; ++r) {
                    int row = row0 + rt * 16 + kgrp * 4 + r;
                    if (row < n) {
                        float v = acc[rt][ct][r] * dv[rt][r];
                        unsigned int u = __float_as_uint(v);
                        u += 0x7fffu + ((u >> 16) & 1u);        // RNE
                        ob[(size_t)row * F + j] = (unsigned short)(u >> 16);
                    }
                }
            }
        }
    } else {
        float* ofp = (float*)outv;
#pragma unroll
        for (int rt = 0; rt < 2; ++rt) {
#pragma unroll
            for (int ct = 0; ct < CT; ++ct) {
                int j = ct * 16 + arow;
                float bv = 0.f;
                if constexpr (BIAS) bv = bias[j];
#pragma unroll
                for (int r = 0; r < 4; ++r) {
                    int row = row0 + rt * 16 + kgrp * 4 + r;
                    if (row < n) {
                        float v = acc[rt][ct][r];
                        if constexpr (BIAS) v += bv;
                        if constexpr (RELU) v = fmaxf(v, 0.f);
                        if constexpr (POSTADD) v += post[(size_t)row * F + j];
                        ofp[(size_t)row * F + j] = v;
                    }
                }
            }
        }
    }
}

// ---------------- GCN aggregation over pre-scaled bf16 features ----------------
// hs[s] = dinv[s]*h[s] in bf16.  out[d] = relu( dinv[d]*(hs[d] + sum_s hs[s]) + bias ).
// half-wave per node; lane owns elements c*4..c*4+3 (8B bf16 loads).

__global__ __launch_bounds__(256) void k_agg_bf(
    const int* __restrict__ rowptr, const int* __restrict__ csr,
    const float* __restrict__ dinv, const unsigned short* __restrict__ hs,
    const float* __restrict__ bias, float* __restrict__ out, int n)
{
    const int node = blockIdx.x * 8 + (threadIdx.x >> 5);
    if (node >= n) return;
    const int c = threadIdx.x & 31;
    const float dd = dinv[node];
    const int beg = rowptr[node];
    const int end = rowptr[node + 1];

    ushort4 sv = *(const ushort4*)(hs + (size_t)node * 128 + c * 4);
    float a0 = __uint_as_float((unsigned int)sv.x << 16);
    float a1 = __uint_as_float((unsigned int)sv.y << 16);
    float a2 = __uint_as_float((unsigned int)sv.z << 16);
    float a3 = __uint_as_float((unsigned int)sv.w << 16);

    int j = beg;
    for (; j + 3 < end; j += 4) {
        int s0 = csr[j], s1 = csr[j + 1], s2 = csr[j + 2], s3 = csr[j + 3];
        ushort4 v0 = *(const ushort4*)(hs + (size_t)s0 * 128 + c * 4);
        ushort4 v1 = *(const ushort4*)(hs + (size_t)s1 * 128 + c * 4);
        ushort4 v2 = *(const ushort4*)(hs + (size_t)s2 * 128 + c * 4);
        ushort4 v3 = *(const ushort4*)(hs + (size_t)s3 * 128 + c * 4);
        a0 += __uint_as_float((unsigned int)v0.x << 16);
        a1 += __uint_as_float((unsigned int)v0.y << 16);
        a2 += __uint_as_float((unsigned int)v0.z << 16);
        a3 += __uint_as_float((unsigned int)v0.w << 16);
        a0 += __uint_as_float((unsigned int)v1.x << 16);
        a1 += __uint_as_float((unsigned int)v1.y << 16);
        a2 += __uint_as_float((unsigned int)v1.z << 16);
        a3 += __uint_as_float((unsigned int)v1.w << 16);
        a0 += __uint_as_float((unsigned int)v2.x << 16);
        a1 += __uint_as_float((unsigned int)v2.y << 16);
        a2 += __uint_as_float((unsigned int)v2.z << 16);
        a3 += __uint_as_float((unsigned int)v2.w << 16);
        a0 += __uint_as_float((unsigned int)v3.x << 16);
        a1 += __uint_as_float((unsigned int)v3.y << 16);
        a2 += __uint_as_float((unsigned int)v3.z << 16);
        a3 += __uint_as_float((unsigned int)v3.w << 16);
    }
    for (; j < end; ++j) {
        int s = csr[j];
        ushort4 v = *(const ushort4*)(hs + (size_t)s * 128 + c * 4);
        a0 += __uint_as_float((unsigned int)v.x << 16);
        a1 += __uint_as_float((unsigned int)v.y << 16);
        a2 += __uint_as_float((unsigned int)v.z << 16);
        a3 += __uint_as_float((unsigned int)v.w << 16);
    }

    float4 bv = ((const float4*)bias)[c];
    float4 o;
    o.x = fmaxf(fmaf(dd, a0, bv.x), 0.f);
    o.y = fmaxf(fmaf(dd, a1, bv.y), 0.f);
    o.z = fmaxf(fmaf(dd, a2, bv.z), 0.f);
    o.w = fmaxf(fmaf(dd, a3, bv.w), 0.f);
    ((float4*)out)[(size_t)node * 32 + c] = o;
}

// ---------------- final small GEMM [n,64]@[64,10] ----------------

__global__ __launch_bounds__(256) void k_final(const float* __restrict__ z7, const float* __restrict__ Wo,
                        const float* __restrict__ bo, float* __restrict__ out, int n) {
    __shared__ float Wos[64][10];
    __shared__ float bos[10];
    if (threadIdx.x < 64) {
#pragma unroll
        for (int j = 0; j < 10; ++j) Wos[threadIdx.x][j] = Wo[threadIdx.x * 10 + j];
        if (threadIdx.x < 10) bos[threadIdx.x] = bo[threadIdx.x];
    }
    __syncthreads();
    int idx = blockIdx.x * blockDim.x + threadIdx.x;
    if (idx >= n * 10) return;
    int row = idx / 10, j = idx % 10;
    const float* zr = z7 + (size_t)row * 64;
    float acc = bos[j];
#pragma unroll
    for (int k = 0; k < 64; ++k) acc = fmaf(zr[k], Wos[k][j], acc);
    out[idx] = acc;
}

// ---------------- launch ----------------

extern "C" void kernel_launch(void* const* d_in, const int* in_sizes, int n_in,
                              void* d_out, int out_size, void* d_ws, size_t ws_size,
                              hipStream_t stream) {
    const float* x   = (const float*)d_in[0];
    const float* gx  = (const float*)d_in[1];
    const void*  ei  = d_in[2];
    const float* W1  = (const float*)d_in[3];  const float* b1  = (const float*)d_in[4];
    const float* Wdr = (const float*)d_in[5];  const float* bdr = (const float*)d_in[6];
    const float* Wg1 = (const float*)d_in[7];  const float* bg1 = (const float*)d_in[8];
    const float* Wg2 = (const float*)d_in[9];  const float* bg2 = (const float*)d_in[10];
    const float* W2  = (const float*)d_in[11]; const float* b2  = (const float*)d_in[12];
    const float* W3  = (const float*)d_in[13]; const float* b3  = (const float*)d_in[14];
    const float* Wo  = (const float*)d_in[15]; const float* bo  = (const float*)d_in[16];
    float* out = (float*)d_out;
    const int n = in_sizes[0] / 128;
    const int E = in_sizes[2] / 2;
    const int twoE = 2 * E;
    const int nb = (n + 511) / 512;

    char* ws = (char*)d_ws;
    size_t off = 0;
    auto alloc = [&](size_t bytes) -> void* {
        void* p = ws + off;
        off = (off + bytes + 255) & ~(size_t)255;
        return p;
    };
    int*   flag   = (int*)  alloc(256);
    int*   cnt    = (int*)  alloc((size_t)n * 4);
    int*   rowptr = (int*)  alloc(((size_t)n + 1) * 4);
    int*   cursor = (int*)  alloc((size_t)n * 4);
    float* dinv   = (float*)alloc((size_t)n * 4);
    int*   bsum   = (int*)  alloc(1024);
    int*   bofs   = (int*)  alloc(1024);
    int*   es     = (int*)  alloc((size_t)twoE * 4);
    int*   ed     = es + E;
    int*   csr    = (int*)  alloc((size_t)E * 4);
    unsigned short* W1H  = (unsigned short*)alloc(256 * 128 * 2);
    unsigned short* W1L  = (unsigned short*)alloc(256 * 128 * 2);
    unsigned short* WdrH = (unsigned short*)alloc(128 * 128 * 2);
    unsigned short* WdrL = (unsigned short*)alloc(128 * 128 * 2);
    unsigned short* Wg1H = (unsigned short*)alloc(128 * 128 * 2);
    unsigned short* Wg1L = (unsigned short*)alloc(128 * 128 * 2);
    unsigned short* Wg2H = (unsigned short*)alloc(128 * 128 * 2);
    unsigned short* Wg2L = (unsigned short*)alloc(128 * 128 * 2);
    unsigned short* W2H  = (unsigned short*)alloc(384 * 128 * 2);
    unsigned short* W2L  = (unsigned short*)alloc(384 * 128 * 2);
    unsigned short* W3H  = (unsigned short*)alloc(128 * 64 * 2);
    unsigned short* W3L  = (unsigned short*)alloc(128 * 64 * 2);
    unsigned short* HS1  = (unsigned short*)alloc((size_t)n * 128 * 2); // dinv-scaled bf16 h1
    unsigned short* HS2  = (unsigned short*)alloc((size_t)n * 128 * 2); // dinv-scaled bf16 h2
    float* B0 = (float*)alloc((size_t)n * 128 * 4); // z
    float* B1 = (float*)alloc((size_t)n * 128 * 4); // z0 -> z7
    float* B2 = (float*)alloc((size_t)n * 128 * 4); // t
    float* B3 = (float*)alloc((size_t)n * 128 * 4); // z1
    float* B4 = (float*)alloc((size_t)n * 128 * 4); // z2
    (void)ws_size; (void)n_in; (void)out_size;

    // edge prep + CSR build
    k_detect<<<1, 64, 0, stream>>>((const unsigned int*)ei, flag);
    hipMemsetAsync(cnt, 0, (size_t)n * 4, stream);
    k_convert_hist<<<(twoE + 255) / 256, 256, 0, stream>>>(ei, twoE, E, flag, es, cnt);
    k_scan1<<<nb, 512, 0, stream>>>(cnt, n, rowptr, bsum);
    k_scan2<<<1, 256, 0, stream>>>(bsum, nb, bofs);
    k_scan3<<<(n + 255) / 256, 256, 0, stream>>>(cnt, n, E, bofs, rowptr, cursor, dinv);
    k_fill_part<<<2048, 256, 0, stream>>>(es, ed, E, n, rowptr, cursor, csr);

    // weight conversions (tiny)
    k_wconv<<<(256 * 128 + 255) / 256, 256, 0, stream>>>(W1,  256, 128, W1H,  W1L);
    k_wconv<<<(128 * 128 + 255) / 256, 256, 0, stream>>>(Wdr, 128, 128, WdrH, WdrL);
    k_wconv<<<(128 * 128 + 255) / 256, 256, 0, stream>>>(Wg1, 128, 128, Wg1H, Wg1L);
    k_wconv<<<(128 * 128 + 255) / 256, 256, 0, stream>>>(Wg2, 128, 128, Wg2H, Wg2L);
    k_wconv<<<(384 * 128 + 255) / 256, 256, 0, stream>>>(W2,  384, 128, W2H,  W2L);
    k_wconv<<<(128 * 64  + 255) / 256, 256, 0, stream>>>(W3,  128, 64,  W3H,  W3L);

    const int gm = (n + 127) / 128;
    const int ga = (n + 7) / 8;
    // z = relu([x|gx] @ W1 + b1)
    k_mgemm<256, 128, 0, true,  true,  false, false><<<gm, 256, 0, stream>>>(x, gx, nullptr, W1H, W1L, b1, nullptr, nullptr, B0, n);
    // z0 = z @ Wdr + bdr
    k_mgemm<128, 128, 0, false, true,  false, false><<<gm, 256, 0, stream>>>(B0, nullptr, nullptr, WdrH, WdrL, bdr, nullptr, nullptr, B1, n);
    // hs1 = dinv * ((z + gx) @ Wg1)   [bf16]
    k_mgemm<128, 128, 1, false, false, true,  false><<<gm, 256, 0, stream>>>(B0, gx, nullptr, Wg1H, Wg1L, nullptr, nullptr, dinv, HS1, n);
    // z1 = relu(dinv * (hs1[d] + sum hs1[s]) + bg1)
    k_agg_bf<<<ga, 256, 0, stream>>>(rowptr, csr, dinv, HS1, bg1, B3, n);
    // hs2 = dinv * (z1 @ Wg2)   [bf16]
    k_mgemm<128, 128, 1, false, false, false, false><<<gm, 256, 0, stream>>>(B3, nullptr, nullptr, Wg2H, Wg2L, nullptr, nullptr, dinv, HS2, n);
    // z2 = relu(dinv * (hs2[d] + sum hs2[s]) + bg2)
    k_agg_bf<<<ga, 256, 0, stream>>>(rowptr, csr, dinv, HS2, bg2, B4, n);
    // t = relu([z|z1|z2] @ W2 + b2) + z0
    k_mgemm<384, 128, 0, true,  true,  false, true ><<<gm, 256, 0, stream>>>(B0, B3, B4, W2H, W2L, b2, B1, nullptr, B2, n);
    // z7 = relu(t @ W3 + b3)
    k_mgemm<128, 64,  0, true,  true,  false, false><<<gm, 256, 0, stream>>>(B2, nullptr, nullptr, W3H, W3L, b3, nullptr, nullptr, B1, n);
    // out = z7 @ Wo + bo
    k_final<<<(n * 10 + 255) / 256, 256, 0, stream>>>(B1, Wo, bo, out, n);
}